// Round 3
// baseline (6561.316 us; speedup 1.0000x reference)
//
#include <hip/hip_runtime.h>

#define NN   50000
#define RR   500
#define MM   120000
#define EE   960000
#define NEE  800000
#define BB   8192
#define DD   200
#define HH1  256
#define HIDD 512
#define OCC  50

typedef unsigned int  u32;
typedef unsigned short u16;

static __device__ __forceinline__ float bf2f(u16 u) {
    u32 x = ((u32)u) << 16;
    return __uint_as_float(x);
}
static __device__ __forceinline__ u16 f2bf(float f) {
    u32 x = __float_as_uint(f);
    u32 r = (x + 0x7FFFu + ((x >> 16) & 1u)) >> 16;
    return (u16)r;
}
static __device__ __forceinline__ u32 pack2(float a, float b) {
    return (u32)f2bf(a) | ((u32)f2bf(b) << 16);
}
static __device__ __forceinline__ void unpack2(u32 v, float& a, float& b) {
    a = bf2f((u16)(v & 0xFFFFu));
    b = bf2f((u16)(v >> 16));
}
// device-scope packed bf16 atomic add
static __device__ __forceinline__ void atomic_pk_bf16(u16* addr, float a, float b) {
    u32 d = pack2(a, b);
    asm volatile("global_atomic_pk_add_bf16 %0, %1, off sc1"
                 :: "v"(addr), "v"(d) : "memory");
}

static __device__ __forceinline__ float wredsum(float v) {
#pragma unroll
    for (int off = 32; off > 0; off >>= 1) v += __shfl_xor(v, off);
    return v;
}

template<typename T> static __device__ __forceinline__ float ldv(const T* p, size_t i);
template<> __device__ __forceinline__ float ldv<float>(const float* p, size_t i) { return p[i]; }
template<> __device__ __forceinline__ float ldv<u16>(const u16* p, size_t i) { return bf2f(p[i]); }
template<typename T> static __device__ __forceinline__ void stv(T* p, size_t i, float v);
template<> __device__ __forceinline__ void stv<float>(float* p, size_t i, float v) { p[i] = v; }
template<> __device__ __forceinline__ void stv<u16>(u16* p, size_t i, float v) { p[i] = f2bf(v); }

// ---------------- l2 normalize rows of [rows, DD]; optional f32 + bf16 outputs ----------------
__global__ void k_l2norm(const float* __restrict__ in, float* __restrict__ outf,
                         u16* __restrict__ outb, int rows) {
    int w = (blockIdx.x * blockDim.x + threadIdx.x) >> 6;
    int lane = threadIdx.x & 63;
    if (w >= rows) return;
    const float* r = in + (size_t)w * DD;
    float s = 0.f;
    for (int d = lane; d < DD; d += 64) { float v = r[d]; s += v * v; }
    s = wredsum(s);
    float inv = 1.0f / fmaxf(sqrtf(s), 1e-12f);
    for (int d = lane; d < DD; d += 64) {
        float v = r[d] * inv;
        if (outf) outf[(size_t)w * DD + d] = v;
        if (outb) outb[(size_t)w * DD + d] = f2bf(v);
    }
}

// ---------------- per-node counts + permuted index ----------------
__global__ void k_cnt_idx(const int* __restrict__ bx, const int* __restrict__ perm,
                          float* __restrict__ cnt, int* __restrict__ idx1, int M) {
    int m = blockIdx.x * blockDim.x + threadIdx.x;
    if (m >= M) return;
    int n = bx[m];
    idx1[m] = perm[n];
    atomicAdd(&cnt[n], 1.0f);
}

// ---------------- edge scatter: out[dst] += (Pent[iv[src]] + Prel[gi[src]]) * w (dim 256 bf16) ----------------
__global__ void k_edge_aggx(const int* __restrict__ src, const int* __restrict__ dst,
                            const float* __restrict__ w, const int* __restrict__ iv,
                            const int* __restrict__ gi, const u16* __restrict__ Pent,
                            const u16* __restrict__ Prel, u16* __restrict__ out, int nE) {
    int g = blockIdx.x * blockDim.x + threadIdx.x;
    int e = g >> 6;
    if (e >= nE) return;
    int lane = g & 63;
    int m = src[e];
    int dn = dst[e];
    float wv = w[e];
    const u32* pe = (const u32*)(Pent + (size_t)iv[m] * HH1);
    const u32* pr = (const u32*)(Prel + (size_t)gi[m] * HH1);
    u16* o = out + (size_t)dn * HH1;
#pragma unroll
    for (int t = 0; t < 2; ++t) {
        int p = lane + t * 64;   // pair index, 128 pairs
        float a0, a1v, b0, b1v;
        unpack2(pe[p], a0, a1v);
        unpack2(pr[p], b0, b1v);
        atomic_pk_bf16(o + 2 * p, (a0 + b0) * wv, (a1v + b1v) * wv);
    }
}

// ---------------- edge scatter bf16->bf16: out[dst] += in[src]*w (dim 200) ----------------
__global__ void k_edge_agg200(const int* __restrict__ src, const int* __restrict__ dst,
                              const float* __restrict__ w, const u16* __restrict__ in,
                              u16* __restrict__ out, int nE) {
    int g = blockIdx.x * blockDim.x + threadIdx.x;
    int e = g >> 6;
    if (e >= nE) return;
    int lane = g & 63;
    int s = src[e];
    int dn = dst[e];
    float wv = w[e];
    const u32* r = (const u32*)(in + (size_t)s * DD);
    u16* o = out + (size_t)dn * DD;
    for (int p = lane; p < DD / 2; p += 64) {
        float a, b;
        unpack2(r[p], a, b);
        atomic_pk_bf16(o + 2 * p, a * wv, b * wv);
    }
}

// ---------------- edge scatter T->f32: out[dst] += in[src]*w (dim 200, f32 atomics) ----------------
template<typename TIN>
__global__ void k_edge_agg200_f(const int* __restrict__ src, const int* __restrict__ dst,
                                const float* __restrict__ w, const TIN* __restrict__ in,
                                float* __restrict__ out, int nE) {
    int g = blockIdx.x * blockDim.x + threadIdx.x;
    int e = g >> 6;
    if (e >= nE) return;
    int lane = g & 63;
    int s = src[e];
    int dn = dst[e];
    float wv = w[e];
    const TIN* r = in + (size_t)s * DD;
    float* o = out + (size_t)dn * DD;
#pragma unroll
    for (int d = lane; d < DD; d += 64)
        atomicAdd(&o[d], ldv(r, d) * wv);
}

// ---------------- scatter rows (unweighted) by idx: out[idx[m]] += in[m] (dim 200 bf16) ----------------
__global__ void k_scatter200(const u16* __restrict__ in, const int* __restrict__ idx,
                             u16* __restrict__ out, int rows) {
    int g = blockIdx.x * blockDim.x + threadIdx.x;
    int m = g >> 6;
    if (m >= rows) return;
    int lane = g & 63;
    int n = idx[m];
    const u32* r = (const u32*)(in + (size_t)m * DD);
    u16* o = out + (size_t)n * DD;
    for (int p = lane; p < DD / 2; p += 64) {
        float a, b;
        unpack2(r[p], a, b);
        atomic_pk_bf16(o + 2 * p, a, b);
    }
}

__global__ void k_scale_mean(u16* __restrict__ mean, const float* __restrict__ cnt) {
    int i = blockIdx.x * blockDim.x + threadIdx.x;  // pair index
    if (i >= NN * (DD / 2)) return;
    int n = i / (DD / 2);
    float inv = 1.0f / fmaxf(cnt[n], 1.0f);
    u32* m32 = (u32*)mean;
    float a, b;
    unpack2(m32[i], a, b);
    m32[i] = pack2(a * inv, b * inv);
}

// pooled[n] = occ(n) ? [e[n], mean[n]] : 0   -> [NN, 2*DD] bf16
__global__ void k_pooled(const u16* __restrict__ e_buf, const u16* __restrict__ meanN,
                         const float* __restrict__ cnt, u16* __restrict__ pooled) {
    int g = blockIdx.x * blockDim.x + threadIdx.x;
    int n = g >> 6;
    if (n >= NN) return;
    int lane = g & 63;
    bool occ = cnt[n] > 0.5f;
    const u32* er = (const u32*)(e_buf + (size_t)n * DD);
    const u32* mr = (const u32*)(meanN + (size_t)n * DD);
    u32* p = (u32*)(pooled + (size_t)n * (2 * DD));
    for (int q = lane; q < DD / 2; q += 64) {
        p[q] = occ ? er[q] : 0u;
        p[DD / 2 + q] = occ ? mr[q] : 0u;
    }
}

// ---------------- tiled matmul: C[Mr,Nc] = op(A[Mr,Kd]) @ B[Kd,Nc](f32) ----------------
template<typename TA, typename TC, int RELU_IN, int RELU_OUT, int HAS_BIAS, int HAS_ADD>
__global__ __launch_bounds__(256) void k_matmul(
    const TA* __restrict__ A, const float* __restrict__ Bw, TC* __restrict__ C,
    int Mr, int Nc, int Kd,
    const float* __restrict__ bias, const u16* __restrict__ addsrc,
    const int* __restrict__ addidx) {
    __shared__ float As[16][68];
    __shared__ float Bs[16][68];
    int tid = threadIdx.x;
    int bm0 = blockIdx.y * 64;
    int bn0 = blockIdx.x * 64;
    int tr = tid >> 4, tc = tid & 15;
    int la_k = tid & 15, la_r = tid >> 4;
    int lb_c = tid & 63, lb_k = tid >> 6;
    float acc[4][4] = {};
    for (int k0 = 0; k0 < Kd; k0 += 16) {
#pragma unroll
        for (int rr = 0; rr < 4; ++rr) {
            int row = bm0 + la_r + rr * 16;
            int kk = k0 + la_k;
            float v = (row < Mr && kk < Kd) ? ldv(A, (size_t)row * Kd + kk) : 0.f;
            if (RELU_IN) v = fmaxf(v, 0.f);
            As[la_k][la_r + rr * 16] = v;
        }
#pragma unroll
        for (int rr = 0; rr < 4; ++rr) {
            int kk = k0 + lb_k + rr * 4;
            int col = bn0 + lb_c;
            Bs[lb_k + rr * 4][lb_c] = (kk < Kd && col < Nc) ? Bw[(size_t)kk * Nc + col] : 0.f;
        }
        __syncthreads();
#pragma unroll
        for (int kk = 0; kk < 16; ++kk) {
            float av[4], bv[4];
#pragma unroll
            for (int i = 0; i < 4; ++i) av[i] = As[kk][tr * 4 + i];
#pragma unroll
            for (int j = 0; j < 4; ++j) bv[j] = Bs[kk][tc * 4 + j];
#pragma unroll
            for (int i = 0; i < 4; ++i)
#pragma unroll
                for (int j = 0; j < 4; ++j) acc[i][j] += av[i] * bv[j];
        }
        __syncthreads();
    }
#pragma unroll
    for (int i = 0; i < 4; ++i) {
        int row = bm0 + tr * 4 + i;
        if (row >= Mr) continue;
#pragma unroll
        for (int j = 0; j < 4; ++j) {
            int col = bn0 + tc * 4 + j;
            if (col >= Nc) continue;
            float v = acc[i][j];
            if (HAS_BIAS) v += bias[col];
            if (RELU_OUT) v = fmaxf(v, 0.f);
            if (HAS_ADD) {
                int r2 = addidx ? addidx[row] : row;
                v += bf2f(addsrc[(size_t)r2 * Nc + col]);
            }
            stv(C, (size_t)row * Nc + col, v);
        }
    }
}

// ---------------- DGI helpers (f32 p-buffer) ----------------
__global__ void k_colsum(const float* __restrict__ p, float* __restrict__ csum, int rows) {
    int c2 = threadIdx.x;  // pair of columns, 256 threads
    int r0 = blockIdx.x * 128;
    int rend = min(r0 + 128, rows);
    float s0 = 0.f, s1 = 0.f;
    for (int r = r0; r < rend; ++r) {
        s0 += p[(size_t)r * HIDD + c2 * 2];
        s1 += p[(size_t)r * HIDD + c2 * 2 + 1];
    }
    atomicAdd(&csum[c2 * 2], s0);
    atomicAdd(&csum[c2 * 2 + 1], s1);
}

__global__ void k_sigc(const float* __restrict__ csum, float* __restrict__ cvec) {
    int i = threadIdx.x;  // 512
    cvec[i] = 1.0f / (1.0f + expf(-csum[i] * (1.0f / (float)NN)));
}

__global__ void k_tmv(const float* __restrict__ Wd, const float* __restrict__ cvec,
                      float* __restrict__ tvec) {
    __shared__ float c[HIDD];
    int lane = threadIdx.x;  // 64
    for (int j = lane; j < HIDD; j += 64) c[j] = cvec[j];
    __syncthreads();
    int r0 = blockIdx.x * 16;
    for (int i = r0; i < r0 + 16; ++i) {
        const float* wr = Wd + (size_t)i * HIDD;
        float s = 0.f;
        for (int j = lane; j < HIDD; j += 64) s += wr[j] * c[j];
        s = wredsum(s);
        if (lane == 0) tvec[i] = s;
    }
}

__global__ void k_rowdot512(const float* __restrict__ p, const float* __restrict__ t,
                            float* __restrict__ out, int rows) {
    int g = blockIdx.x * blockDim.x + threadIdx.x;
    int wv = g >> 6;
    if (wv >= rows) return;
    int lane = g & 63;
    const float* r = p + (size_t)wv * HIDD;
    float s = 0.f;
#pragma unroll
    for (int t4 = 0; t4 < 8; ++t4) {
        int d = lane + t4 * 64;
        s += r[d] * t[d];
    }
    s = wredsum(s);
    if (lane == 0) out[wv] = s;
}

// ---------------- ConvKB ----------------
__global__ void k_convkb(const u16* __restrict__ ec, const float* __restrict__ rel,
                         const int* __restrict__ bi, const float* __restrict__ cw,
                         const float* __restrict__ cb, const float* __restrict__ fcw,
                         const float* __restrict__ fcb, float* __restrict__ out) {
    __shared__ float t0[DD], t1[DD], t2[DD];
    __shared__ float red[4];
    int b = blockIdx.x, tid = threadIdx.x;
    int i0 = bi[b * 3 + 0], i1 = bi[b * 3 + 1], i2 = bi[b * 3 + 2];
    if (tid < DD) {
        t0[tid] = bf2f(ec[(size_t)i0 * DD + tid]);
        t1[tid] = rel[(size_t)i1 * DD + tid];
        t2[tid] = bf2f(ec[(size_t)i2 * DD + tid]);
    }
    __syncthreads();
    float partial = 0.f;
    if (tid < DD) {
        float a = t0[tid], bb = t1[tid], c = t2[tid];
        for (int o = 0; o < OCC; ++o) {
            float h = fmaxf(cw[o * 3 + 0] * a + cw[o * 3 + 1] * bb + cw[o * 3 + 2] * c + cb[o], 0.f);
            partial += h * fcw[o * DD + tid];
        }
    }
    partial = wredsum(partial);
    if ((tid & 63) == 0) red[tid >> 6] = partial;
    __syncthreads();
    if (tid == 0) out[b] = red[0] + red[1] + red[2] + red[3] + fcb[0];
}

__global__ void k_sentinel(float* out, float val) { out[threadIdx.x] = val; }

extern "C" void kernel_launch(void* const* d_in, const int* in_sizes, int n_in,
                              void* d_out, int out_size, void* d_ws, size_t ws_size,
                              hipStream_t stream) {
    const float* entity_emb = (const float*)d_in[0];
    const float* rel_emb    = (const float*)d_in[1];
    const int*   b_x        = (const int*)d_in[2];
    const int*   b_gi       = (const int*)d_in[3];
    const int*   e_src      = (const int*)d_in[4];
    const int*   e_dst      = (const int*)d_in[5];
    const float* e_w        = (const float*)d_in[6];
    const int*   big_src    = (const int*)d_in[7];
    const int*   big_dst    = (const int*)d_in[8];
    const float* big_w      = (const float*)d_in[9];
    const int*   perm       = (const int*)d_in[10];
    const int*   batch_in   = (const int*)d_in[11];
    const float* W1a        = (const float*)d_in[12];
    const float* W1b        = (const float*)d_in[13];
    const float* W2a        = (const float*)d_in[14];
    const float* W2b        = (const float*)d_in[15];
    // Wle/ble unused: segment softmax weights sum to exactly 1 and every row in a
    // segment shares the same emb vector -> pooled[n] == occ(n)*concat(e[n],mean[n])
    const float* Wlo        = (const float*)d_in[18];
    const float* blo        = (const float*)d_in[19];
    const float* Wg         = (const float*)d_in[20];
    const float* Wd         = (const float*)d_in[21];
    const float* conv_w     = (const float*)d_in[22];
    const float* conv_b     = (const float*)d_in[23];
    const float* fc_w       = (const float*)d_in[24];
    const float* fc_b       = (const float*)d_in[25];
    float* out = (float*)d_out;

    // ---- byte-based workspace layout ----
    const size_t SZ_ENTB = (size_t)NN * DD * 2;       // 20.0 MB bf16
    const size_t SZ_RELF = (size_t)RR * DD * 4;
    const size_t SZ_RELB = (size_t)RR * DD * 2;
    const size_t SZ_PENT = (size_t)NN * HH1 * 2;      // 25.6 MB
    const size_t SZ_PREL = (size_t)RR * HH1 * 2;
    const size_t SZ_CNT  = (size_t)NN * 4;
    const size_t SZ_IDX  = (size_t)MM * 4;
    const size_t SZ_EC   = (size_t)NN * DD * 2;       // 20 MB (ec / ecs per pass)
    const size_t SZ_A    = (size_t)MM * HH1 * 2;      // 61.44 MB
    const size_t SZ_B    = (size_t)MM * DD * 2;       // 48 MB
    const size_t SZ_C    = (size_t)MM * DD * 2;       // 48 MB
    const size_t SZ_VEC  = 4 * 2048;

    size_t off = 0;
    auto balloc = [&](size_t nbytes) {
        size_t p = off;
        off += (nbytes + 511) & ~(size_t)511;
        return p;
    };
    char* base = (char*)d_ws;
    u16*   entb = (u16*)(base + balloc(SZ_ENTB));
    float* relf = (float*)(base + balloc(SZ_RELF));
    u16*   relb = (u16*)(base + balloc(SZ_RELB));
    u16*   Pent = (u16*)(base + balloc(SZ_PENT));
    u16*   Prel = (u16*)(base + balloc(SZ_PREL));
    float* cnt  = (float*)(base + balloc(SZ_CNT));
    int*   idx1 = (int*)(base + balloc(SZ_IDX));
    u16*   ecb  = (u16*)(base + balloc(SZ_EC));
    char*  Aarena = base + balloc(SZ_A);
    char*  Barena = base + balloc(SZ_B);
    char*  Carena = base + balloc(SZ_C);
    float* csum = (float*)(base + balloc(SZ_VEC));
    float* cvec = csum + 512;
    float* t_l  = csum + 1024;
    float* t_g  = csum + 1536;

    if (ws_size < off) {  // encode actual ws size (MB) for diagnosis
        k_sentinel<<<dim3(1), dim3(8), 0, stream>>>(out, (float)(ws_size >> 20));
        return;
    }

    // arena sub-views (liveness-based time sharing; A,B,C are contiguous)
    u16*   aggx   = (u16*)Aarena;                     // [MM,256] bf16, MCE
    u16*   pooled = (u16*)Aarena;                     // [NN,400] bf16 (40 MB)
    u16*   meanN  = (u16*)(Aarena + 40000000);        // [NN,200] bf16 (20 MB)
    u16*   hb     = (u16*)Barena;                     // [MM,200] bf16
    u16*   e_buf  = (u16*)Carena;                     // [MM,200] bf16
    float* a1f    = (float*)Aarena;                   // [NN,200] f32 (40 MB)
    float* h2f    = (float*)Barena;                   // [NN,256] f32 (51.2 MB, spans into C)
    float* h2bf   = (float*)Aarena;                   // [NN,200] f32 (40 MB, a1 dead)
    float* egf    = (float*)Carena;                   // [NN,200] f32 (40 MB, h2 dead)
    float* pbuf   = (float*)Aarena;                   // [NN,512] f32 (102.4 MB, spans A+B)

    dim3 blk(256);
    auto wgrid = [](int items) { return dim3((unsigned)((items + 3) / 4)); };

    // normalize
    k_l2norm<<<wgrid(NN), blk, 0, stream>>>(entity_emb, nullptr, entb, NN);
    k_l2norm<<<wgrid(RR), blk, 0, stream>>>(rel_emb, relf, relb, RR);
    hipMemsetAsync(cnt, 0, SZ_CNT, stream);
    k_cnt_idx<<<dim3((MM + 255) / 256), blk, 0, stream>>>(b_x, perm, cnt, idx1, MM);

    // P_ent = ent @ W1a[:200], P_rel = rel @ W1a[200:]
    k_matmul<u16, u16, 0, 0, 0, 0><<<dim3(HH1 / 64, (NN + 63) / 64), blk, 0, stream>>>(
        entb, W1a, Pent, NN, HH1, DD, nullptr, nullptr, nullptr);
    k_matmul<u16, u16, 0, 0, 0, 0><<<dim3(HH1 / 64, (RR + 63) / 64), blk, 0, stream>>>(
        relb, W1a + (size_t)DD * HH1, Prel, RR, HH1, DD, nullptr, nullptr, nullptr);

    for (int v = 0; v < 2; ++v) {
        const int* ivmap  = v ? idx1 : b_x;
        const int* addidx = v ? perm : nullptr;

        // --- MCE (bf16 path; validated) ---
        hipMemsetAsync(aggx, 0, SZ_A, stream);
        k_edge_aggx<<<wgrid(EE), blk, 0, stream>>>(e_src, e_dst, e_w, ivmap, b_gi,
                                                   Pent, Prel, aggx, EE);
        k_matmul<u16, u16, 1, 0, 0, 0><<<dim3((DD + 63) / 64, (MM + 63) / 64), blk, 0, stream>>>(
            aggx, W1b, hb, MM, DD, HH1, nullptr, nullptr, nullptr);
        hipMemsetAsync(e_buf, 0, SZ_C, stream);
        k_edge_agg200<<<wgrid(EE), blk, 0, stream>>>(e_src, e_dst, e_w, hb, e_buf, EE);
        hipMemsetAsync(meanN, 0, (size_t)NN * DD * 2, stream);
        k_scatter200<<<wgrid(MM), blk, 0, stream>>>(e_buf, b_x, meanN, MM);
        k_scale_mean<<<dim3((NN * (DD / 2) + 255) / 256), blk, 0, stream>>>(meanN, cnt);
        k_pooled<<<wgrid(NN), blk, 0, stream>>>(e_buf, meanN, cnt, pooled);
        // ec_v = pooled @ Wlo + blo + ent[addidx]
        k_matmul<u16, u16, 0, 0, 1, 1><<<dim3((DD + 63) / 64, (NN + 63) / 64), blk, 0, stream>>>(
            pooled, Wlo, ecb, NN, DD, 2 * DD, blo, entb, addidx);

        // --- DGI local: p = relu(ecv @ Wg)  (f32 p-buffer in A+B span) ---
        k_matmul<u16, float, 0, 1, 0, 0><<<dim3(HIDD / 64, (NN + 63) / 64), blk, 0, stream>>>(
            ecb, Wg, pbuf, NN, HIDD, DD, nullptr, nullptr, nullptr);
        if (v == 0) {
            hipMemsetAsync(csum, 0, 512 * sizeof(float), stream);
            k_colsum<<<dim3((NN + 127) / 128), blk, 0, stream>>>(pbuf, csum, NN);
            k_sigc<<<dim3(1), dim3(512), 0, stream>>>(csum, cvec);
            k_tmv<<<dim3(32), dim3(64), 0, stream>>>(Wd, cvec, t_l);
        }
        k_rowdot512<<<wgrid(NN), blk, 0, stream>>>(pbuf, t_l, out + BB + (size_t)v * NN, NN);

        if (v == 0) {  // ConvKB needs ec (v0) — run before buffer reuse
            k_convkb<<<dim3(BB), blk, 0, stream>>>(ecb, relf, batch_in,
                                                   conv_w, conv_b, fc_w, fc_b, out);
        }

        // --- big GCN, all-f32 chain: eg = agg(relu(agg(ec)@W2a)@W2b) ---
        hipMemsetAsync(a1f, 0, (size_t)NN * DD * 4, stream);
        k_edge_agg200_f<u16><<<wgrid(NEE), blk, 0, stream>>>(big_src, big_dst, big_w,
                                                             ecb, a1f, NEE);
        k_matmul<float, float, 0, 1, 0, 0><<<dim3(HH1 / 64, (NN + 63) / 64), blk, 0, stream>>>(
            a1f, W2a, h2f, NN, HH1, DD, nullptr, nullptr, nullptr);
        k_matmul<float, float, 0, 0, 0, 0><<<dim3((DD + 63) / 64, (NN + 63) / 64), blk, 0, stream>>>(
            h2f, W2b, h2bf, NN, DD, HH1, nullptr, nullptr, nullptr);
        hipMemsetAsync(egf, 0, (size_t)NN * DD * 4, stream);
        k_edge_agg200_f<float><<<wgrid(NEE), blk, 0, stream>>>(big_src, big_dst, big_w,
                                                               h2bf, egf, NEE);

        // --- DGI global: p = relu(egv @ Wg)  (pbuf overwrites h2bf: dead) ---
        k_matmul<float, float, 0, 1, 0, 0><<<dim3(HIDD / 64, (NN + 63) / 64), blk, 0, stream>>>(
            egf, Wg, pbuf, NN, HIDD, DD, nullptr, nullptr, nullptr);
        if (v == 0) {
            hipMemsetAsync(csum, 0, 512 * sizeof(float), stream);
            k_colsum<<<dim3((NN + 127) / 128), blk, 0, stream>>>(pbuf, csum, NN);
            k_sigc<<<dim3(1), dim3(512), 0, stream>>>(csum, cvec);
            k_tmv<<<dim3(32), dim3(64), 0, stream>>>(Wd, cvec, t_g);
        }
        k_rowdot512<<<wgrid(NN), blk, 0, stream>>>(pbuf, t_g,
                                                   out + BB + 2 * (size_t)NN + (size_t)v * NN, NN);
    }

    (void)in_sizes; (void)n_in; (void)out_size;
}

// Round 4
// 3841.003 us; speedup vs baseline: 1.7082x; 1.7082x over previous
//
#include <hip/hip_runtime.h>

#define NN   50000
#define RR   500
#define MM   120000
#define EE   960000
#define NEE  800000
#define BB   8192
#define DD   200
#define HH1  256
#define HIDD 512
#define OCC  50

typedef unsigned int  u32;
typedef unsigned short u16;

static __device__ __forceinline__ float bf2f(u16 u) {
    u32 x = ((u32)u) << 16;
    return __uint_as_float(x);
}
static __device__ __forceinline__ u16 f2bf(float f) {
    u32 x = __float_as_uint(f);
    u32 r = (x + 0x7FFFu + ((x >> 16) & 1u)) >> 16;
    return (u16)r;
}
static __device__ __forceinline__ u32 pack2(float a, float b) {
    return (u32)f2bf(a) | ((u32)f2bf(b) << 16);
}
static __device__ __forceinline__ void unpack2(u32 v, float& a, float& b) {
    a = bf2f((u16)(v & 0xFFFFu));
    b = bf2f((u16)(v >> 16));
}

static __device__ __forceinline__ float wredsum(float v) {
#pragma unroll
    for (int off = 32; off > 0; off >>= 1) v += __shfl_xor(v, off);
    return v;
}

template<typename T> static __device__ __forceinline__ float ldv(const T* p, size_t i);
template<> __device__ __forceinline__ float ldv<float>(const float* p, size_t i) { return p[i]; }
template<> __device__ __forceinline__ float ldv<u16>(const u16* p, size_t i) { return bf2f(p[i]); }
template<typename T> static __device__ __forceinline__ void stv(T* p, size_t i, float v);
template<> __device__ __forceinline__ void stv<float>(float* p, size_t i, float v) { p[i] = v; }
template<> __device__ __forceinline__ void stv<u16>(u16* p, size_t i, float v) { p[i] = f2bf(v); }

// ---------------- l2 normalize rows of [rows, DD] ----------------
__global__ void k_l2norm(const float* __restrict__ in, float* __restrict__ outf,
                         u16* __restrict__ outb, int rows) {
    int w = (blockIdx.x * blockDim.x + threadIdx.x) >> 6;
    int lane = threadIdx.x & 63;
    if (w >= rows) return;
    const float* r = in + (size_t)w * DD;
    float s = 0.f;
    for (int d = lane; d < DD; d += 64) { float v = r[d]; s += v * v; }
    s = wredsum(s);
    float inv = 1.0f / fmaxf(sqrtf(s), 1e-12f);
    for (int d = lane; d < DD; d += 64) {
        float v = r[d] * inv;
        if (outf) outf[(size_t)w * DD + d] = v;
        if (outb) outb[(size_t)w * DD + d] = f2bf(v);
    }
}

__global__ void k_gather_perm(const int* __restrict__ bx, const int* __restrict__ perm,
                              int* __restrict__ idx1, int M) {
    int m = blockIdx.x * blockDim.x + threadIdx.x;
    if (m < M) idx1[m] = perm[bx[m]];
}

// ---------------- CSR build: hist + scan + fill ----------------
__global__ void k_hist(const int* __restrict__ idx, int* __restrict__ cnt, int n) {
    int i = blockIdx.x * blockDim.x + threadIdx.x;
    if (i < n) atomicAdd(&cnt[idx[i]], 1);
}

// exclusive scan of n ints (out has n+1 entries), single block of 1024
__global__ __launch_bounds__(1024) void k_scan(const int* __restrict__ in,
                                               int* __restrict__ out, int n) {
    __shared__ int wtot[16];
    __shared__ int wexc[16];
    __shared__ int s_carry;
    int tid = threadIdx.x, lane = tid & 63, wid = tid >> 6;
    if (tid == 0) s_carry = 0;
    __syncthreads();
    for (int base = 0; base < n; base += 1024) {
        int i = base + tid;
        int v = (i < n) ? in[i] : 0;
        int x = v;
#pragma unroll
        for (int off = 1; off < 64; off <<= 1) {
            int t = __shfl_up(x, off);
            if (lane >= off) x += t;
        }
        if (lane == 63) wtot[wid] = x;
        __syncthreads();
        if (wid == 0) {
            int wv2 = (lane < 16) ? wtot[lane] : 0;
            int y = wv2;
#pragma unroll
            for (int off = 1; off < 16; off <<= 1) {
                int t = __shfl_up(y, off);
                if (lane >= off) y += t;
            }
            if (lane < 16) wexc[lane] = y - wv2;
            if (lane == 15) wtot[15] = y;   // chunk total
        }
        __syncthreads();
        if (i < n) out[i] = s_carry + wexc[wid] + (x - v);
        int chunk_total = wtot[15];
        __syncthreads();
        if (tid == 0) s_carry += chunk_total;
        __syncthreads();
    }
    if (threadIdx.x == 0) out[n] = s_carry;
}

__global__ void k_fill2(const int* __restrict__ dst, const int* __restrict__ src,
                        const float* __restrict__ w, int* __restrict__ cursor,
                        int* __restrict__ srcs_out, float* __restrict__ ws_out, int n) {
    int e = blockIdx.x * blockDim.x + threadIdx.x;
    if (e >= n) return;
    int p = atomicAdd(&cursor[dst[e]], 1);
    srcs_out[p] = src[e];
    ws_out[p] = w[e];
}

__global__ void k_fill1(const int* __restrict__ idx, int* __restrict__ cursor,
                        int* __restrict__ outm, int n) {
    int m = blockIdx.x * blockDim.x + threadIdx.x;
    if (m >= n) return;
    int p = atomicAdd(&cursor[idx[m]], 1);
    outm[p] = m;
}

// ---------------- comb[m] = Pent[iv[m]] + Prel[gi[m]]  (256-dim bf16) ----------------
__global__ void k_combine(const int* __restrict__ iv, const int* __restrict__ gi,
                          const u16* __restrict__ Pent, const u16* __restrict__ Prel,
                          u16* __restrict__ comb, int M) {
    int m = (blockIdx.x * blockDim.x + threadIdx.x) >> 6;
    int lane = threadIdx.x & 63;
    if (m >= M) return;
    const u32* pe = (const u32*)(Pent + (size_t)iv[m] * HH1);
    const u32* pr = (const u32*)(Prel + (size_t)gi[m] * HH1);
    u32* o = (u32*)(comb + (size_t)m * HH1);
#pragma unroll
    for (int t = 0; t < 2; ++t) {
        int p = lane + 64 * t;
        float a, b, c, d;
        unpack2(pe[p], a, b);
        unpack2(pr[p], c, d);
        o[p] = pack2(a + c, b + d);
    }
}

// ---------------- CSR pull: out[i] = sum_e w[e]*in[srcs[e]]  (one wave per dst row) ----------------
template<int DIMS, typename TIN, typename TOUT>
__global__ void k_pull(const int* __restrict__ rp, const int* __restrict__ srcs,
                       const float* __restrict__ wsrt, const TIN* __restrict__ in,
                       TOUT* __restrict__ out, int ndst) {
    int wv = (blockIdx.x * blockDim.x + threadIdx.x) >> 6;
    if (wv >= ndst) return;
    int lane = threadIdx.x & 63;
    int beg = rp[wv], end = rp[wv + 1];
    constexpr int NP = DIMS / 2;            // pairs per row
    constexpr int NT = (NP + 63) / 64;      // pair-slots per lane
    float accA[NT], accB[NT];
#pragma unroll
    for (int t = 0; t < NT; ++t) { accA[t] = 0.f; accB[t] = 0.f; }
    for (int e = beg; e < end; ++e) {
        int s = srcs[e];
        float w = wsrt[e];
        if constexpr (sizeof(TIN) == 2) {
            const u32* r = (const u32*)((const u16*)in + (size_t)s * DIMS);
#pragma unroll
            for (int t = 0; t < NT; ++t) {
                int p = lane + 64 * t;
                if (p < NP) { float a, b; unpack2(r[p], a, b); accA[t] += a * w; accB[t] += b * w; }
            }
        } else {
            const float2* r = (const float2*)((const float*)in + (size_t)s * DIMS);
#pragma unroll
            for (int t = 0; t < NT; ++t) {
                int p = lane + 64 * t;
                if (p < NP) { float2 v = r[p]; accA[t] += v.x * w; accB[t] += v.y * w; }
            }
        }
    }
    if constexpr (sizeof(TOUT) == 2) {
        u32* o = (u32*)((u16*)out + (size_t)wv * DIMS);
#pragma unroll
        for (int t = 0; t < NT; ++t) {
            int p = lane + 64 * t;
            if (p < NP) o[p] = pack2(accA[t], accB[t]);
        }
    } else {
        float2* o = (float2*)((float*)out + (size_t)wv * DIMS);
#pragma unroll
        for (int t = 0; t < NT; ++t) {
            int p = lane + 64 * t;
            if (p < NP) { float2 v; v.x = accA[t]; v.y = accB[t]; o[p] = v; }
        }
    }
}

// ---------------- fused segment mean + pooled: pooled[n]=[occ*e[n], occ*mean_seg(n)] ----------------
__global__ void k_segpool(const int* __restrict__ rpX, const int* __restrict__ mids,
                          const u16* __restrict__ e_buf, u16* __restrict__ pooled, int n) {
    int nv = (blockIdx.x * blockDim.x + threadIdx.x) >> 6;
    if (nv >= n) return;
    int lane = threadIdx.x & 63;
    int beg = rpX[nv], end = rpX[nv + 1];
    int cnt = end - beg;
    float accA[2] = {0.f, 0.f}, accB[2] = {0.f, 0.f};
    for (int e = beg; e < end; ++e) {
        const u32* r = (const u32*)(e_buf + (size_t)mids[e] * DD);
#pragma unroll
        for (int t = 0; t < 2; ++t) {
            int p = lane + 64 * t;
            if (p < DD / 2) { float a, b; unpack2(r[p], a, b); accA[t] += a; accB[t] += b; }
        }
    }
    float inv = 1.0f / fmaxf((float)cnt, 1.0f);
    bool occ = cnt > 0;
    const u32* er = (const u32*)(e_buf + (size_t)nv * DD);
    u32* p0 = (u32*)(pooled + (size_t)nv * (2 * DD));
#pragma unroll
    for (int t = 0; t < 2; ++t) {
        int p = lane + 64 * t;
        if (p < DD / 2) {
            p0[p] = occ ? er[p] : 0u;
            p0[DD / 2 + p] = occ ? pack2(accA[t] * inv, accB[t] * inv) : 0u;
        }
    }
}

// ---------------- tiled matmul: C[Mr,Nc] = op(A[Mr,Kd]) @ B[Kd,Nc](f32) ----------------
template<typename TA, typename TC, int RELU_IN, int RELU_OUT, int HAS_BIAS, int HAS_ADD>
__global__ __launch_bounds__(256) void k_matmul(
    const TA* __restrict__ A, const float* __restrict__ Bw, TC* __restrict__ C,
    int Mr, int Nc, int Kd,
    const float* __restrict__ bias, const u16* __restrict__ addsrc,
    const int* __restrict__ addidx) {
    __shared__ float As[16][68];
    __shared__ float Bs[16][68];
    int tid = threadIdx.x;
    int bm0 = blockIdx.y * 64;
    int bn0 = blockIdx.x * 64;
    int tr = tid >> 4, tc = tid & 15;
    int la_k = tid & 15, la_r = tid >> 4;
    int lb_c = tid & 63, lb_k = tid >> 6;
    float acc[4][4] = {};
    for (int k0 = 0; k0 < Kd; k0 += 16) {
#pragma unroll
        for (int rr = 0; rr < 4; ++rr) {
            int row = bm0 + la_r + rr * 16;
            int kk = k0 + la_k;
            float v = (row < Mr && kk < Kd) ? ldv(A, (size_t)row * Kd + kk) : 0.f;
            if (RELU_IN) v = fmaxf(v, 0.f);
            As[la_k][la_r + rr * 16] = v;
        }
#pragma unroll
        for (int rr = 0; rr < 4; ++rr) {
            int kk = k0 + lb_k + rr * 4;
            int col = bn0 + lb_c;
            Bs[lb_k + rr * 4][lb_c] = (kk < Kd && col < Nc) ? Bw[(size_t)kk * Nc + col] : 0.f;
        }
        __syncthreads();
#pragma unroll
        for (int kk = 0; kk < 16; ++kk) {
            float av[4], bv[4];
#pragma unroll
            for (int i = 0; i < 4; ++i) av[i] = As[kk][tr * 4 + i];
#pragma unroll
            for (int j = 0; j < 4; ++j) bv[j] = Bs[kk][tc * 4 + j];
#pragma unroll
            for (int i = 0; i < 4; ++i)
#pragma unroll
                for (int j = 0; j < 4; ++j) acc[i][j] += av[i] * bv[j];
        }
        __syncthreads();
    }
#pragma unroll
    for (int i = 0; i < 4; ++i) {
        int row = bm0 + tr * 4 + i;
        if (row >= Mr) continue;
#pragma unroll
        for (int j = 0; j < 4; ++j) {
            int col = bn0 + tc * 4 + j;
            if (col >= Nc) continue;
            float v = acc[i][j];
            if (HAS_BIAS) v += bias[col];
            if (RELU_OUT) v = fmaxf(v, 0.f);
            if (HAS_ADD) {
                int r2 = addidx ? addidx[row] : row;
                v += bf2f(addsrc[(size_t)r2 * Nc + col]);
            }
            stv(C, (size_t)row * Nc + col, v);
        }
    }
}

// ---------------- DGI helpers (f32 p-buffer) ----------------
__global__ void k_colsum(const float* __restrict__ p, float* __restrict__ csum, int rows) {
    int c2 = threadIdx.x;
    int r0 = blockIdx.x * 128;
    int rend = min(r0 + 128, rows);
    float s0 = 0.f, s1 = 0.f;
    for (int r = r0; r < rend; ++r) {
        s0 += p[(size_t)r * HIDD + c2 * 2];
        s1 += p[(size_t)r * HIDD + c2 * 2 + 1];
    }
    atomicAdd(&csum[c2 * 2], s0);
    atomicAdd(&csum[c2 * 2 + 1], s1);
}

__global__ void k_sigc(const float* __restrict__ csum, float* __restrict__ cvec) {
    int i = threadIdx.x;
    cvec[i] = 1.0f / (1.0f + expf(-csum[i] * (1.0f / (float)NN)));
}

__global__ void k_tmv(const float* __restrict__ Wd, const float* __restrict__ cvec,
                      float* __restrict__ tvec) {
    __shared__ float c[HIDD];
    int lane = threadIdx.x;
    for (int j = lane; j < HIDD; j += 64) c[j] = cvec[j];
    __syncthreads();
    int r0 = blockIdx.x * 16;
    for (int i = r0; i < r0 + 16; ++i) {
        const float* wr = Wd + (size_t)i * HIDD;
        float s = 0.f;
        for (int j = lane; j < HIDD; j += 64) s += wr[j] * c[j];
        s = wredsum(s);
        if (lane == 0) tvec[i] = s;
    }
}

__global__ void k_rowdot512(const float* __restrict__ p, const float* __restrict__ t,
                            float* __restrict__ out, int rows) {
    int g = blockIdx.x * blockDim.x + threadIdx.x;
    int wv = g >> 6;
    if (wv >= rows) return;
    int lane = g & 63;
    const float* r = p + (size_t)wv * HIDD;
    float s = 0.f;
#pragma unroll
    for (int t4 = 0; t4 < 8; ++t4) {
        int d = lane + t4 * 64;
        s += r[d] * t[d];
    }
    s = wredsum(s);
    if (lane == 0) out[wv] = s;
}

// ---------------- ConvKB ----------------
__global__ void k_convkb(const u16* __restrict__ ec, const float* __restrict__ rel,
                         const int* __restrict__ bi, const float* __restrict__ cw,
                         const float* __restrict__ cb, const float* __restrict__ fcw,
                         const float* __restrict__ fcb, float* __restrict__ out) {
    __shared__ float t0[DD], t1[DD], t2[DD];
    __shared__ float red[4];
    int b = blockIdx.x, tid = threadIdx.x;
    int i0 = bi[b * 3 + 0], i1 = bi[b * 3 + 1], i2 = bi[b * 3 + 2];
    if (tid < DD) {
        t0[tid] = bf2f(ec[(size_t)i0 * DD + tid]);
        t1[tid] = rel[(size_t)i1 * DD + tid];
        t2[tid] = bf2f(ec[(size_t)i2 * DD + tid]);
    }
    __syncthreads();
    float partial = 0.f;
    if (tid < DD) {
        float a = t0[tid], bb = t1[tid], c = t2[tid];
        for (int o = 0; o < OCC; ++o) {
            float h = fmaxf(cw[o * 3 + 0] * a + cw[o * 3 + 1] * bb + cw[o * 3 + 2] * c + cb[o], 0.f);
            partial += h * fcw[o * DD + tid];
        }
    }
    partial = wredsum(partial);
    if ((tid & 63) == 0) red[tid >> 6] = partial;
    __syncthreads();
    if (tid == 0) out[b] = red[0] + red[1] + red[2] + red[3] + fcb[0];
}

__global__ void k_sentinel(float* out, float val) { out[threadIdx.x] = val; }

extern "C" void kernel_launch(void* const* d_in, const int* in_sizes, int n_in,
                              void* d_out, int out_size, void* d_ws, size_t ws_size,
                              hipStream_t stream) {
    const float* entity_emb = (const float*)d_in[0];
    const float* rel_emb    = (const float*)d_in[1];
    const int*   b_x        = (const int*)d_in[2];
    const int*   b_gi       = (const int*)d_in[3];
    const int*   e_src      = (const int*)d_in[4];
    const int*   e_dst      = (const int*)d_in[5];
    const float* e_w        = (const float*)d_in[6];
    const int*   big_src    = (const int*)d_in[7];
    const int*   big_dst    = (const int*)d_in[8];
    const float* big_w      = (const float*)d_in[9];
    const int*   perm       = (const int*)d_in[10];
    const int*   batch_in   = (const int*)d_in[11];
    const float* W1a        = (const float*)d_in[12];
    const float* W1b        = (const float*)d_in[13];
    const float* W2a        = (const float*)d_in[14];
    const float* W2b        = (const float*)d_in[15];
    // Wle/ble unused: segment softmax weights sum to exactly 1 and every row in a
    // segment shares the same emb vector -> pooled[n] == occ(n)*concat(e[n],mean[n])
    const float* Wlo        = (const float*)d_in[18];
    const float* blo        = (const float*)d_in[19];
    const float* Wg         = (const float*)d_in[20];
    const float* Wd         = (const float*)d_in[21];
    const float* conv_w     = (const float*)d_in[22];
    const float* conv_b     = (const float*)d_in[23];
    const float* fc_w       = (const float*)d_in[24];
    const float* fc_b       = (const float*)d_in[25];
    float* out = (float*)d_out;

    size_t off = 0;
    auto balloc = [&](size_t nbytes) {
        size_t p = off;
        off += (nbytes + 511) & ~(size_t)511;
        return p;
    };
    char* base = (char*)d_ws;
    u16*   entb = (u16*)(base + balloc((size_t)NN * DD * 2));
    float* relf = (float*)(base + balloc((size_t)RR * DD * 4));
    u16*   relb = (u16*)(base + balloc((size_t)RR * DD * 2));
    u16*   Pent = (u16*)(base + balloc((size_t)NN * HH1 * 2));
    u16*   Prel = (u16*)(base + balloc((size_t)RR * HH1 * 2));
    int*   idx1 = (int*)(base + balloc((size_t)MM * 4));
    u16*   ecb  = (u16*)(base + balloc((size_t)NN * DD * 2));
    // CSR structures (persistent across both passes)
    int*   rpB  = (int*)(base + balloc((size_t)(NN + 1) * 4));
    int*   srcB = (int*)(base + balloc((size_t)NEE * 4));
    float* wB   = (float*)(base + balloc((size_t)NEE * 4));
    int*   rpE  = (int*)(base + balloc((size_t)(MM + 1) * 4));
    int*   srcE = (int*)(base + balloc((size_t)EE * 4));
    float* wE   = (float*)(base + balloc((size_t)EE * 4));
    int*   rpX  = (int*)(base + balloc((size_t)(NN + 1) * 4));
    int*   mids = (int*)(base + balloc((size_t)MM * 4));
    int*   curB = (int*)(base + balloc((size_t)NN * 4));
    int*   curE = (int*)(base + balloc((size_t)MM * 4));
    int*   curX = (int*)(base + balloc((size_t)NN * 4));
    // arenas (A,B,C contiguous; A+B hosts pbuf 102.4MB, B+C hosts comb 61.4MB / h2f 51.2MB)
    char*  Aarena = base + balloc((size_t)MM * HH1 * 2);   // 61.44 MB
    char*  Barena = base + balloc((size_t)MM * DD * 2);    // 48 MB
    char*  Carena = base + balloc((size_t)MM * DD * 2);    // 48 MB
    float* csum = (float*)(base + balloc(4 * 2048));
    float* cvec = csum + 512;
    float* t_l  = csum + 1024;
    float* t_g  = csum + 1536;

    if (ws_size < off) {  // encode actual ws size (MB) for diagnosis
        k_sentinel<<<dim3(1), dim3(8), 0, stream>>>(out, (float)(ws_size >> 20));
        return;
    }

    u16*   aggx   = (u16*)Aarena;                 // [MM,256] bf16
    u16*   comb   = (u16*)Barena;                 // [MM,256] bf16 (spans B..C)
    u16*   hb     = (u16*)Barena;                 // [MM,200] bf16 (comb dead)
    u16*   e_buf  = (u16*)Carena;                 // [MM,200] bf16
    u16*   pooled = (u16*)Aarena;                 // [NN,400] bf16 (aggx dead)
    float* a1f    = (float*)Aarena;               // [NN,200] f32
    float* h2f    = (float*)Barena;               // [NN,256] f32 (spans B..C)
    float* h2bf   = (float*)Aarena;               // [NN,200] f32
    float* egf    = (float*)Carena;               // [NN,200] f32
    float* pbuf   = (float*)Aarena;               // [NN,512] f32 (spans A..B)

    dim3 blk(256);
    auto wgrid = [](int items) { return dim3((unsigned)((items + 3) / 4)); };
    auto tgrid = [](int items) { return dim3((unsigned)((items + 255) / 256)); };

    // ---- normalize + perm gather ----
    k_l2norm<<<wgrid(NN), blk, 0, stream>>>(entity_emb, nullptr, entb, NN);
    k_l2norm<<<wgrid(RR), blk, 0, stream>>>(rel_emb, relf, relb, RR);
    k_gather_perm<<<tgrid(MM), blk, 0, stream>>>(b_x, perm, idx1, MM);

    // ---- CSR builds (hist -> scan -> cursor copy -> fill) ----
    hipMemsetAsync(curB, 0, (size_t)NN * 4, stream);
    hipMemsetAsync(curE, 0, (size_t)MM * 4, stream);
    hipMemsetAsync(curX, 0, (size_t)NN * 4, stream);
    k_hist<<<tgrid(NEE), blk, 0, stream>>>(big_dst, curB, NEE);
    k_hist<<<tgrid(EE), blk, 0, stream>>>(e_dst, curE, EE);
    k_hist<<<tgrid(MM), blk, 0, stream>>>(b_x, curX, MM);
    k_scan<<<dim3(1), dim3(1024), 0, stream>>>(curB, rpB, NN);
    k_scan<<<dim3(1), dim3(1024), 0, stream>>>(curE, rpE, MM);
    k_scan<<<dim3(1), dim3(1024), 0, stream>>>(curX, rpX, NN);
    hipMemcpyAsync(curB, rpB, (size_t)NN * 4, hipMemcpyDeviceToDevice, stream);
    hipMemcpyAsync(curE, rpE, (size_t)MM * 4, hipMemcpyDeviceToDevice, stream);
    hipMemcpyAsync(curX, rpX, (size_t)NN * 4, hipMemcpyDeviceToDevice, stream);
    k_fill2<<<tgrid(NEE), blk, 0, stream>>>(big_dst, big_src, big_w, curB, srcB, wB, NEE);
    k_fill2<<<tgrid(EE), blk, 0, stream>>>(e_dst, e_src, e_w, curE, srcE, wE, EE);
    k_fill1<<<tgrid(MM), blk, 0, stream>>>(b_x, curX, mids, MM);

    // ---- P_ent = ent @ W1a[:200], P_rel = rel @ W1a[200:] ----
    k_matmul<u16, u16, 0, 0, 0, 0><<<dim3(HH1 / 64, (NN + 63) / 64), blk, 0, stream>>>(
        entb, W1a, Pent, NN, HH1, DD, nullptr, nullptr, nullptr);
    k_matmul<u16, u16, 0, 0, 0, 0><<<dim3(HH1 / 64, (RR + 63) / 64), blk, 0, stream>>>(
        relb, W1a + (size_t)DD * HH1, Prel, RR, HH1, DD, nullptr, nullptr, nullptr);

    for (int v = 0; v < 2; ++v) {
        const int* ivmap  = v ? idx1 : b_x;
        const int* addidx = v ? perm : nullptr;

        // --- MCE via pull aggregation ---
        k_combine<<<wgrid(MM), blk, 0, stream>>>(ivmap, b_gi, Pent, Prel, comb, MM);
        k_pull<HH1, u16, u16><<<wgrid(MM), blk, 0, stream>>>(rpE, srcE, wE, comb, aggx, MM);
        k_matmul<u16, u16, 1, 0, 0, 0><<<dim3((DD + 63) / 64, (MM + 63) / 64), blk, 0, stream>>>(
            aggx, W1b, hb, MM, DD, HH1, nullptr, nullptr, nullptr);
        k_pull<DD, u16, u16><<<wgrid(MM), blk, 0, stream>>>(rpE, srcE, wE, hb, e_buf, MM);
        k_segpool<<<wgrid(NN), blk, 0, stream>>>(rpX, mids, e_buf, pooled, NN);
        k_matmul<u16, u16, 0, 0, 1, 1><<<dim3((DD + 63) / 64, (NN + 63) / 64), blk, 0, stream>>>(
            pooled, Wlo, ecb, NN, DD, 2 * DD, blo, entb, addidx);

        // --- DGI local ---
        k_matmul<u16, float, 0, 1, 0, 0><<<dim3(HIDD / 64, (NN + 63) / 64), blk, 0, stream>>>(
            ecb, Wg, pbuf, NN, HIDD, DD, nullptr, nullptr, nullptr);
        if (v == 0) {
            hipMemsetAsync(csum, 0, 512 * sizeof(float), stream);
            k_colsum<<<dim3((NN + 127) / 128), blk, 0, stream>>>(pbuf, csum, NN);
            k_sigc<<<dim3(1), dim3(512), 0, stream>>>(csum, cvec);
            k_tmv<<<dim3(32), dim3(64), 0, stream>>>(Wd, cvec, t_l);
        }
        k_rowdot512<<<wgrid(NN), blk, 0, stream>>>(pbuf, t_l, out + BB + (size_t)v * NN, NN);

        if (v == 0) {
            k_convkb<<<dim3(BB), blk, 0, stream>>>(ecb, relf, batch_in,
                                                   conv_w, conv_b, fc_w, fc_b, out);
        }

        // --- big GCN (f32 chain) via pulls ---
        k_pull<DD, u16, float><<<wgrid(NN), blk, 0, stream>>>(rpB, srcB, wB, ecb, a1f, NN);
        k_matmul<float, float, 0, 1, 0, 0><<<dim3(HH1 / 64, (NN + 63) / 64), blk, 0, stream>>>(
            a1f, W2a, h2f, NN, HH1, DD, nullptr, nullptr, nullptr);
        k_matmul<float, float, 0, 0, 0, 0><<<dim3((DD + 63) / 64, (NN + 63) / 64), blk, 0, stream>>>(
            h2f, W2b, h2bf, NN, DD, HH1, nullptr, nullptr, nullptr);
        k_pull<DD, float, float><<<wgrid(NN), blk, 0, stream>>>(rpB, srcB, wB, h2bf, egf, NN);

        // --- DGI global ---
        k_matmul<float, float, 0, 1, 0, 0><<<dim3(HIDD / 64, (NN + 63) / 64), blk, 0, stream>>>(
            egf, Wg, pbuf, NN, HIDD, DD, nullptr, nullptr, nullptr);
        if (v == 0) {
            hipMemsetAsync(csum, 0, 512 * sizeof(float), stream);
            k_colsum<<<dim3((NN + 127) / 128), blk, 0, stream>>>(pbuf, csum, NN);
            k_sigc<<<dim3(1), dim3(512), 0, stream>>>(csum, cvec);
            k_tmv<<<dim3(32), dim3(64), 0, stream>>>(Wd, cvec, t_g);
        }
        k_rowdot512<<<wgrid(NN), blk, 0, stream>>>(pbuf, t_g,
                                                   out + BB + 2 * (size_t)NN + (size_t)v * NN, NN);
    }

    (void)in_sizes; (void)n_in; (void)out_size;
}

// Round 5
// 3170.865 us; speedup vs baseline: 2.0693x; 1.2113x over previous
//
#include <hip/hip_runtime.h>

#define NN   50000
#define RR   500
#define MM   120000
#define EE   960000
#define NEE  800000
#define BB   8192
#define DD   200
#define HH1  256
#define HIDD 512
#define OCC  50

typedef unsigned int  u32;
typedef unsigned short u16;
typedef __attribute__((ext_vector_type(8))) short bf16x8;
typedef __attribute__((ext_vector_type(4))) float f32x4;

static __device__ __forceinline__ float bf2f(u16 u) {
    u32 x = ((u32)u) << 16;
    return __uint_as_float(x);
}
static __device__ __forceinline__ u16 f2bf(float f) {
    u32 x = __float_as_uint(f);
    u32 r = (x + 0x7FFFu + ((x >> 16) & 1u)) >> 16;
    return (u16)r;
}
static __device__ __forceinline__ u32 pack2(float a, float b) {
    return (u32)f2bf(a) | ((u32)f2bf(b) << 16);
}
static __device__ __forceinline__ void unpack2(u32 v, float& a, float& b) {
    a = bf2f((u16)(v & 0xFFFFu));
    b = bf2f((u16)(v >> 16));
}

static __device__ __forceinline__ float wredsum(float v) {
#pragma unroll
    for (int off = 32; off > 0; off >>= 1) v += __shfl_xor(v, off);
    return v;
}

template<typename T> static __device__ __forceinline__ void stv(T* p, size_t i, float v);
template<> __device__ __forceinline__ void stv<float>(float* p, size_t i, float v) { p[i] = v; }
template<> __device__ __forceinline__ void stv<u16>(u16* p, size_t i, float v) { p[i] = f2bf(v); }

static __device__ __forceinline__ u32 relu2bf(u32 x) {
    if (x & 0x00008000u) x &= 0xFFFF0000u;
    if (x & 0x80000000u) x &= 0x0000FFFFu;
    return x;
}

// ---------------- l2 normalize rows of [rows, DD] ----------------
__global__ void k_l2norm(const float* __restrict__ in, float* __restrict__ outf,
                         u16* __restrict__ outb, int rows) {
    int w = (blockIdx.x * blockDim.x + threadIdx.x) >> 6;
    int lane = threadIdx.x & 63;
    if (w >= rows) return;
    const float* r = in + (size_t)w * DD;
    float s = 0.f;
    for (int d = lane; d < DD; d += 64) { float v = r[d]; s += v * v; }
    s = wredsum(s);
    float inv = 1.0f / fmaxf(sqrtf(s), 1e-12f);
    for (int d = lane; d < DD; d += 64) {
        float v = r[d] * inv;
        if (outf) outf[(size_t)w * DD + d] = v;
        if (outb) outb[(size_t)w * DD + d] = f2bf(v);
    }
}

__global__ void k_gather_perm(const int* __restrict__ bx, const int* __restrict__ perm,
                              int* __restrict__ idx1, int M) {
    int m = blockIdx.x * blockDim.x + threadIdx.x;
    if (m < M) idx1[m] = perm[bx[m]];
}

// ---------------- CSR build: hist + scan + fill ----------------
__global__ void k_hist(const int* __restrict__ idx, int* __restrict__ cnt, int n) {
    int i = blockIdx.x * blockDim.x + threadIdx.x;
    if (i < n) atomicAdd(&cnt[idx[i]], 1);
}

__global__ __launch_bounds__(1024) void k_scan(const int* __restrict__ in,
                                               int* __restrict__ out, int n) {
    __shared__ int wtot[16];
    __shared__ int wexc[16];
    __shared__ int s_carry;
    int tid = threadIdx.x, lane = tid & 63, wid = tid >> 6;
    if (tid == 0) s_carry = 0;
    __syncthreads();
    for (int base = 0; base < n; base += 1024) {
        int i = base + tid;
        int v = (i < n) ? in[i] : 0;
        int x = v;
#pragma unroll
        for (int off = 1; off < 64; off <<= 1) {
            int t = __shfl_up(x, off);
            if (lane >= off) x += t;
        }
        if (lane == 63) wtot[wid] = x;
        __syncthreads();
        if (wid == 0) {
            int wv2 = (lane < 16) ? wtot[lane] : 0;
            int y = wv2;
#pragma unroll
            for (int off = 1; off < 16; off <<= 1) {
                int t = __shfl_up(y, off);
                if (lane >= off) y += t;
            }
            if (lane < 16) wexc[lane] = y - wv2;
            if (lane == 15) wtot[15] = y;
        }
        __syncthreads();
        if (i < n) out[i] = s_carry + wexc[wid] + (x - v);
        int chunk_total = wtot[15];
        __syncthreads();
        if (tid == 0) s_carry += chunk_total;
        __syncthreads();
    }
    if (threadIdx.x == 0) out[n] = s_carry;
}

__global__ void k_fill2(const int* __restrict__ dst, const int* __restrict__ src,
                        const float* __restrict__ w, int* __restrict__ cursor,
                        int* __restrict__ srcs_out, float* __restrict__ ws_out, int n) {
    int e = blockIdx.x * blockDim.x + threadIdx.x;
    if (e >= n) return;
    int p = atomicAdd(&cursor[dst[e]], 1);
    srcs_out[p] = src[e];
    ws_out[p] = w[e];
}

__global__ void k_fill1(const int* __restrict__ idx, int* __restrict__ cursor,
                        int* __restrict__ outm, int n) {
    int m = blockIdx.x * blockDim.x + threadIdx.x;
    if (m >= n) return;
    int p = atomicAdd(&cursor[idx[m]], 1);
    outm[p] = m;
}

// ---------------- comb[m] = Pent[iv[m]] + Prel[gi[m]]  (256-dim bf16) ----------------
__global__ void k_combine(const int* __restrict__ iv, const int* __restrict__ gi,
                          const u16* __restrict__ Pent, const u16* __restrict__ Prel,
                          u16* __restrict__ comb, int M) {
    int m = (blockIdx.x * blockDim.x + threadIdx.x) >> 6;
    int lane = threadIdx.x & 63;
    if (m >= M) return;
    const u32* pe = (const u32*)(Pent + (size_t)iv[m] * HH1);
    const u32* pr = (const u32*)(Prel + (size_t)gi[m] * HH1);
    u32* o = (u32*)(comb + (size_t)m * HH1);
#pragma unroll
    for (int t = 0; t < 2; ++t) {
        int p = lane + 64 * t;
        float a, b, c, d;
        unpack2(pe[p], a, b);
        unpack2(pr[p], c, d);
        o[p] = pack2(a + c, b + d);
    }
}

// ---------------- CSR pull: out[i] = sum_e w[e]*in[srcs[e]]  (one wave per dst row) ----------------
template<int DIMS, typename TIN, typename TOUT>
__global__ void k_pull(const int* __restrict__ rp, const int* __restrict__ srcs,
                       const float* __restrict__ wsrt, const TIN* __restrict__ in,
                       TOUT* __restrict__ out, int ndst) {
    int wv = (blockIdx.x * blockDim.x + threadIdx.x) >> 6;
    if (wv >= ndst) return;
    int lane = threadIdx.x & 63;
    int beg = rp[wv], end = rp[wv + 1];
    constexpr int NP = DIMS / 2;
    constexpr int NT = (NP + 63) / 64;
    float accA[NT], accB[NT];
#pragma unroll
    for (int t = 0; t < NT; ++t) { accA[t] = 0.f; accB[t] = 0.f; }
    for (int e = beg; e < end; ++e) {
        int s = srcs[e];
        float w = wsrt[e];
        if constexpr (sizeof(TIN) == 2) {
            const u32* r = (const u32*)((const u16*)in + (size_t)s * DIMS);
#pragma unroll
            for (int t = 0; t < NT; ++t) {
                int p = lane + 64 * t;
                if (p < NP) { float a, b; unpack2(r[p], a, b); accA[t] += a * w; accB[t] += b * w; }
            }
        } else {
            const float2* r = (const float2*)((const float*)in + (size_t)s * DIMS);
#pragma unroll
            for (int t = 0; t < NT; ++t) {
                int p = lane + 64 * t;
                if (p < NP) { float2 v = r[p]; accA[t] += v.x * w; accB[t] += v.y * w; }
            }
        }
    }
    if constexpr (sizeof(TOUT) == 2) {
        u32* o = (u32*)((u16*)out + (size_t)wv * DIMS);
#pragma unroll
        for (int t = 0; t < NT; ++t) {
            int p = lane + 64 * t;
            if (p < NP) o[p] = pack2(accA[t], accB[t]);
        }
    } else {
        float2* o = (float2*)((float*)out + (size_t)wv * DIMS);
#pragma unroll
        for (int t = 0; t < NT; ++t) {
            int p = lane + 64 * t;
            if (p < NP) { float2 v; v.x = accA[t]; v.y = accB[t]; o[p] = v; }
        }
    }
}

// ---------------- fused segment mean + pooled ----------------
__global__ void k_segpool(const int* __restrict__ rpX, const int* __restrict__ mids,
                          const u16* __restrict__ e_buf, u16* __restrict__ pooled, int n) {
    int nv = (blockIdx.x * blockDim.x + threadIdx.x) >> 6;
    if (nv >= n) return;
    int lane = threadIdx.x & 63;
    int beg = rpX[nv], end = rpX[nv + 1];
    int cnt = end - beg;
    float accA[2] = {0.f, 0.f}, accB[2] = {0.f, 0.f};
    for (int e = beg; e < end; ++e) {
        const u32* r = (const u32*)(e_buf + (size_t)mids[e] * DD);
#pragma unroll
        for (int t = 0; t < 2; ++t) {
            int p = lane + 64 * t;
            if (p < DD / 2) { float a, b; unpack2(r[p], a, b); accA[t] += a; accB[t] += b; }
        }
    }
    float inv = 1.0f / fmaxf((float)cnt, 1.0f);
    bool occ = cnt > 0;
    const u32* er = (const u32*)(e_buf + (size_t)nv * DD);
    u32* p0 = (u32*)(pooled + (size_t)nv * (2 * DD));
#pragma unroll
    for (int t = 0; t < 2; ++t) {
        int p = lane + 64 * t;
        if (p < DD / 2) {
            p0[p] = occ ? er[p] : 0u;
            p0[DD / 2 + p] = occ ? pack2(accA[t] * inv, accB[t] * inv) : 0u;
        }
    }
}

// ---------------- MFMA matmul: C[Mr,Nc] = op(A) @ B, split-precision bf16 ----------------
// AMODE 0: A is bf16 storage (no extra A error); B split hi+lo (2 MFMA)
// AMODE 1: A is f32 (split hi+lo); B split hi; 3 MFMA terms (~f32 precision)
template<int AMODE, int RELU_IN, int RELU_OUT, int HAS_BIAS, int HAS_ADD, typename TC>
__global__ __launch_bounds__(256) void k_mfmamm(
    const void* __restrict__ Av, const float* __restrict__ Bw, TC* __restrict__ C,
    int Mr, int Nc, int Kd,
    const float* __restrict__ bias, const u16* __restrict__ addsrc,
    const int* __restrict__ addidx) {
    constexpr int BM = 128, BN = 64, BK = 32;
    constexpr int ASTR = 40;  // u16 units, 80B rows (non-pow2 bank stride)
    __shared__ u16 Ahi[BM * ASTR];
    __shared__ u16 Alo[AMODE ? (BM * ASTR) : 8];
    __shared__ u16 Bhi[BN * ASTR];
    __shared__ u16 Blo[BN * ASTR];

    int tid = threadIdx.x;
    int wid = tid >> 6, lane = tid & 63;
    int wr = wid >> 1, wc = wid & 1;
    int r = lane & 15, h = lane >> 4;
    int bm0 = blockIdx.y * BM, bn0 = blockIdx.x * BN;

    f32x4 acc[4][2];
#pragma unroll
    for (int i = 0; i < 4; ++i)
#pragma unroll
        for (int j = 0; j < 2; ++j) acc[i][j] = (f32x4){0.f, 0.f, 0.f, 0.f};

    for (int k0 = 0; k0 < Kd; k0 += BK) {
        __syncthreads();
        // ---- stage A tile [BM x BK] ----
        {
            int row = tid >> 1, half = tid & 1;
            int gr = bm0 + row;
            int kc = k0 + half * 16;
            u16* dstA = Ahi + row * ASTR + half * 16;
            if (AMODE == 0) {
                const u16* Ab = (const u16*)Av;
                if (gr < Mr && kc + 16 <= Kd) {
                    const uint4* srcp = (const uint4*)(Ab + (size_t)gr * Kd + kc);
                    uint4 v0 = srcp[0], v1 = srcp[1];
                    if (RELU_IN) {
                        v0.x = relu2bf(v0.x); v0.y = relu2bf(v0.y);
                        v0.z = relu2bf(v0.z); v0.w = relu2bf(v0.w);
                        v1.x = relu2bf(v1.x); v1.y = relu2bf(v1.y);
                        v1.z = relu2bf(v1.z); v1.w = relu2bf(v1.w);
                    }
                    ((uint4*)dstA)[0] = v0;
                    ((uint4*)dstA)[1] = v1;
                } else {
#pragma unroll
                    for (int q = 0; q < 16; ++q) {
                        int kk = kc + q;
                        u16 u = (gr < Mr && kk < Kd) ? Ab[(size_t)gr * Kd + kk] : (u16)0;
                        if (RELU_IN && (u & 0x8000u)) u = 0;
                        dstA[q] = u;
                    }
                }
            } else {
                const float* Af = (const float*)Av;
                u16* dstL = Alo + row * ASTR + half * 16;
                if (gr < Mr && kc + 16 <= Kd) {
                    const float4* srcp = (const float4*)(Af + (size_t)gr * Kd + kc);
#pragma unroll
                    for (int s4 = 0; s4 < 4; ++s4) {
                        float4 v = srcp[s4];
                        float vs[4] = {v.x, v.y, v.z, v.w};
#pragma unroll
                        for (int q = 0; q < 4; ++q) {
                            u16 hi = f2bf(vs[q]);
                            dstA[s4 * 4 + q] = hi;
                            dstL[s4 * 4 + q] = f2bf(vs[q] - bf2f(hi));
                        }
                    }
                } else {
#pragma unroll
                    for (int q = 0; q < 16; ++q) {
                        int kk = kc + q;
                        float a = (gr < Mr && kk < Kd) ? Af[(size_t)gr * Kd + kk] : 0.f;
                        u16 hi = f2bf(a);
                        dstA[q] = hi;
                        dstL[q] = f2bf(a - bf2f(hi));
                    }
                }
            }
        }
        // ---- stage B tile [BK x BN] transposed+split into Bt[n][k] ----
        {
            int kb = tid >> 3;
            int nb = (tid & 7) * 8;
            int gk = k0 + kb;
#pragma unroll
            for (int q = 0; q < 8; ++q) {
                int gn = bn0 + nb + q;
                float b = (gk < Kd && gn < Nc) ? Bw[(size_t)gk * Nc + gn] : 0.f;
                u16 hi = f2bf(b);
                Bhi[(nb + q) * ASTR + kb] = hi;
                Blo[(nb + q) * ASTR + kb] = f2bf(b - bf2f(hi));
            }
        }
        __syncthreads();
        // ---- MFMA ----
        bf16x8 af[4], al[4], bh[2], bl[2];
#pragma unroll
        for (int j = 0; j < 2; ++j) {
            int nrow = wc * 32 + j * 16 + r;
            bh[j] = *(const bf16x8*)(Bhi + nrow * ASTR + h * 8);
            bl[j] = *(const bf16x8*)(Blo + nrow * ASTR + h * 8);
        }
#pragma unroll
        for (int i = 0; i < 4; ++i) {
            int mrow = wr * 64 + i * 16 + r;
            af[i] = *(const bf16x8*)(Ahi + mrow * ASTR + h * 8);
            if (AMODE) al[i] = *(const bf16x8*)(Alo + mrow * ASTR + h * 8);
        }
#pragma unroll
        for (int i = 0; i < 4; ++i)
#pragma unroll
            for (int j = 0; j < 2; ++j) {
                acc[i][j] = __builtin_amdgcn_mfma_f32_16x16x32_bf16(af[i], bh[j], acc[i][j], 0, 0, 0);
                acc[i][j] = __builtin_amdgcn_mfma_f32_16x16x32_bf16(af[i], bl[j], acc[i][j], 0, 0, 0);
                if (AMODE)
                    acc[i][j] = __builtin_amdgcn_mfma_f32_16x16x32_bf16(al[i], bh[j], acc[i][j], 0, 0, 0);
            }
    }
    // ---- epilogue: D col=lane&15, row=4*(lane>>4)+reg ----
#pragma unroll
    for (int i = 0; i < 4; ++i) {
#pragma unroll
        for (int j = 0; j < 2; ++j) {
            int col = bn0 + wc * 32 + j * 16 + r;
            if (col >= Nc) continue;
            int rowb = bm0 + wr * 64 + i * 16 + h * 4;
#pragma unroll
            for (int rg = 0; rg < 4; ++rg) {
                int row = rowb + rg;
                if (row >= Mr) continue;
                float v = acc[i][j][rg];
                if (HAS_BIAS) v += bias[col];
                if (RELU_OUT) v = fmaxf(v, 0.f);
                if (HAS_ADD) {
                    int r2 = addidx ? addidx[row] : row;
                    v += bf2f(addsrc[(size_t)r2 * Nc + col]);
                }
                stv(C, (size_t)row * Nc + col, v);
            }
        }
    }
}

// ---------------- DGI helpers (f32 p-buffer) ----------------
__global__ void k_colsum(const float* __restrict__ p, float* __restrict__ csum, int rows) {
    int c2 = threadIdx.x;
    int r0 = blockIdx.x * 128;
    int rend = min(r0 + 128, rows);
    float s0 = 0.f, s1 = 0.f;
    for (int r = r0; r < rend; ++r) {
        s0 += p[(size_t)r * HIDD + c2 * 2];
        s1 += p[(size_t)r * HIDD + c2 * 2 + 1];
    }
    atomicAdd(&csum[c2 * 2], s0);
    atomicAdd(&csum[c2 * 2 + 1], s1);
}

__global__ void k_sigc(const float* __restrict__ csum, float* __restrict__ cvec) {
    int i = threadIdx.x;
    cvec[i] = 1.0f / (1.0f + expf(-csum[i] * (1.0f / (float)NN)));
}

__global__ void k_tmv(const float* __restrict__ Wd, const float* __restrict__ cvec,
                      float* __restrict__ tvec) {
    __shared__ float c[HIDD];
    int lane = threadIdx.x;
    for (int j = lane; j < HIDD; j += 64) c[j] = cvec[j];
    __syncthreads();
    int r0 = blockIdx.x * 16;
    for (int i = r0; i < r0 + 16; ++i) {
        const float* wr = Wd + (size_t)i * HIDD;
        float s = 0.f;
        for (int j = lane; j < HIDD; j += 64) s += wr[j] * c[j];
        s = wredsum(s);
        if (lane == 0) tvec[i] = s;
    }
}

__global__ void k_rowdot512(const float* __restrict__ p, const float* __restrict__ t,
                            float* __restrict__ out, int rows) {
    int g = blockIdx.x * blockDim.x + threadIdx.x;
    int wv = g >> 6;
    if (wv >= rows) return;
    int lane = g & 63;
    const float* r = p + (size_t)wv * HIDD;
    float s = 0.f;
#pragma unroll
    for (int t4 = 0; t4 < 8; ++t4) {
        int d = lane + t4 * 64;
        s += r[d] * t[d];
    }
    s = wredsum(s);
    if (lane == 0) out[wv] = s;
}

// ---------------- ConvKB ----------------
__global__ void k_convkb(const u16* __restrict__ ec, const float* __restrict__ rel,
                         const int* __restrict__ bi, const float* __restrict__ cw,
                         const float* __restrict__ cb, const float* __restrict__ fcw,
                         const float* __restrict__ fcb, float* __restrict__ out) {
    __shared__ float t0[DD], t1[DD], t2[DD];
    __shared__ float red[4];
    int b = blockIdx.x, tid = threadIdx.x;
    int i0 = bi[b * 3 + 0], i1 = bi[b * 3 + 1], i2 = bi[b * 3 + 2];
    if (tid < DD) {
        t0[tid] = bf2f(ec[(size_t)i0 * DD + tid]);
        t1[tid] = rel[(size_t)i1 * DD + tid];
        t2[tid] = bf2f(ec[(size_t)i2 * DD + tid]);
    }
    __syncthreads();
    float partial = 0.f;
    if (tid < DD) {
        float a = t0[tid], bb = t1[tid], c = t2[tid];
        for (int o = 0; o < OCC; ++o) {
            float h = fmaxf(cw[o * 3 + 0] * a + cw[o * 3 + 1] * bb + cw[o * 3 + 2] * c + cb[o], 0.f);
            partial += h * fcw[o * DD + tid];
        }
    }
    partial = wredsum(partial);
    if ((tid & 63) == 0) red[tid >> 6] = partial;
    __syncthreads();
    if (tid == 0) out[b] = red[0] + red[1] + red[2] + red[3] + fcb[0];
}

__global__ void k_sentinel(float* out, float val) { out[threadIdx.x] = val; }

extern "C" void kernel_launch(void* const* d_in, const int* in_sizes, int n_in,
                              void* d_out, int out_size, void* d_ws, size_t ws_size,
                              hipStream_t stream) {
    const float* entity_emb = (const float*)d_in[0];
    const float* rel_emb    = (const float*)d_in[1];
    const int*   b_x        = (const int*)d_in[2];
    const int*   b_gi       = (const int*)d_in[3];
    const int*   e_src      = (const int*)d_in[4];
    const int*   e_dst      = (const int*)d_in[5];
    const float* e_w        = (const float*)d_in[6];
    const int*   big_src    = (const int*)d_in[7];
    const int*   big_dst    = (const int*)d_in[8];
    const float* big_w      = (const float*)d_in[9];
    const int*   perm       = (const int*)d_in[10];
    const int*   batch_in   = (const int*)d_in[11];
    const float* W1a        = (const float*)d_in[12];
    const float* W1b        = (const float*)d_in[13];
    const float* W2a        = (const float*)d_in[14];
    const float* W2b        = (const float*)d_in[15];
    // Wle/ble unused: segment softmax weights sum to exactly 1 and every row in a
    // segment shares the same emb vector -> pooled[n] == occ(n)*concat(e[n],mean[n])
    const float* Wlo        = (const float*)d_in[18];
    const float* blo        = (const float*)d_in[19];
    const float* Wg         = (const float*)d_in[20];
    const float* Wd         = (const float*)d_in[21];
    const float* conv_w     = (const float*)d_in[22];
    const float* conv_b     = (const float*)d_in[23];
    const float* fc_w       = (const float*)d_in[24];
    const float* fc_b       = (const float*)d_in[25];
    float* out = (float*)d_out;

    size_t off = 0;
    auto balloc = [&](size_t nbytes) {
        size_t p = off;
        off += (nbytes + 511) & ~(size_t)511;
        return p;
    };
    char* base = (char*)d_ws;
    u16*   entb = (u16*)(base + balloc((size_t)NN * DD * 2));
    float* relf = (float*)(base + balloc((size_t)RR * DD * 4));
    u16*   relb = (u16*)(base + balloc((size_t)RR * DD * 2));
    u16*   Pent = (u16*)(base + balloc((size_t)NN * HH1 * 2));
    u16*   Prel = (u16*)(base + balloc((size_t)RR * HH1 * 2));
    int*   idx1 = (int*)(base + balloc((size_t)MM * 4));
    u16*   ecb  = (u16*)(base + balloc((size_t)NN * DD * 2));
    int*   rpB  = (int*)(base + balloc((size_t)(NN + 1) * 4));
    int*   srcB = (int*)(base + balloc((size_t)NEE * 4));
    float* wB   = (float*)(base + balloc((size_t)NEE * 4));
    int*   rpE  = (int*)(base + balloc((size_t)(MM + 1) * 4));
    int*   srcE = (int*)(base + balloc((size_t)EE * 4));
    float* wE   = (float*)(base + balloc((size_t)EE * 4));
    int*   rpX  = (int*)(base + balloc((size_t)(NN + 1) * 4));
    int*   mids = (int*)(base + balloc((size_t)MM * 4));
    int*   curB = (int*)(base + balloc((size_t)NN * 4));
    int*   curE = (int*)(base + balloc((size_t)MM * 4));
    int*   curX = (int*)(base + balloc((size_t)NN * 4));
    char*  Aarena = base + balloc((size_t)MM * HH1 * 2);   // 61.44 MB
    char*  Barena = base + balloc((size_t)MM * DD * 2);    // 48 MB
    char*  Carena = base + balloc((size_t)MM * DD * 2);    // 48 MB
    float* csum = (float*)(base + balloc(4 * 2048));
    float* cvec = csum + 512;
    float* t_l  = csum + 1024;
    float* t_g  = csum + 1536;

    if (ws_size < off) {
        k_sentinel<<<dim3(1), dim3(8), 0, stream>>>(out, (float)(ws_size >> 20));
        return;
    }

    u16*   aggx   = (u16*)Aarena;                 // [MM,256] bf16
    u16*   comb   = (u16*)Barena;                 // [MM,256] bf16 (spans B..C)
    u16*   hb     = (u16*)Barena;                 // [MM,200] bf16 (comb dead)
    u16*   e_buf  = (u16*)Carena;                 // [MM,200] bf16
    u16*   pooled = (u16*)Aarena;                 // [NN,400] bf16 (aggx dead)
    float* a1f    = (float*)Aarena;               // [NN,200] f32
    float* h2f    = (float*)Barena;               // [NN,256] f32 (spans B..C)
    float* h2bf   = (float*)Aarena;               // [NN,200] f32
    float* egf    = (float*)Carena;               // [NN,200] f32
    float* pbuf   = (float*)Aarena;               // [NN,512] f32 (spans A..B)

    dim3 blk(256);
    auto wgrid = [](int items) { return dim3((unsigned)((items + 3) / 4)); };
    auto tgrid = [](int items) { return dim3((unsigned)((items + 255) / 256)); };
    auto mmgrid = [](int Mr, int Nc) { return dim3((unsigned)((Nc + 63) / 64), (unsigned)((Mr + 127) / 128)); };

    // ---- normalize + perm gather ----
    k_l2norm<<<wgrid(NN), blk, 0, stream>>>(entity_emb, nullptr, entb, NN);
    k_l2norm<<<wgrid(RR), blk, 0, stream>>>(rel_emb, relf, relb, RR);
    k_gather_perm<<<tgrid(MM), blk, 0, stream>>>(b_x, perm, idx1, MM);

    // ---- CSR builds ----
    hipMemsetAsync(curB, 0, (size_t)NN * 4, stream);
    hipMemsetAsync(curE, 0, (size_t)MM * 4, stream);
    hipMemsetAsync(curX, 0, (size_t)NN * 4, stream);
    k_hist<<<tgrid(NEE), blk, 0, stream>>>(big_dst, curB, NEE);
    k_hist<<<tgrid(EE), blk, 0, stream>>>(e_dst, curE, EE);
    k_hist<<<tgrid(MM), blk, 0, stream>>>(b_x, curX, MM);
    k_scan<<<dim3(1), dim3(1024), 0, stream>>>(curB, rpB, NN);
    k_scan<<<dim3(1), dim3(1024), 0, stream>>>(curE, rpE, MM);
    k_scan<<<dim3(1), dim3(1024), 0, stream>>>(curX, rpX, NN);
    hipMemcpyAsync(curB, rpB, (size_t)NN * 4, hipMemcpyDeviceToDevice, stream);
    hipMemcpyAsync(curE, rpE, (size_t)MM * 4, hipMemcpyDeviceToDevice, stream);
    hipMemcpyAsync(curX, rpX, (size_t)NN * 4, hipMemcpyDeviceToDevice, stream);
    k_fill2<<<tgrid(NEE), blk, 0, stream>>>(big_dst, big_src, big_w, curB, srcB, wB, NEE);
    k_fill2<<<tgrid(EE), blk, 0, stream>>>(e_dst, e_src, e_w, curE, srcE, wE, EE);
    k_fill1<<<tgrid(MM), blk, 0, stream>>>(b_x, curX, mids, MM);

    // ---- P_ent = ent @ W1a[:200], P_rel = rel @ W1a[200:] ----
    k_mfmamm<0, 0, 0, 0, 0, u16><<<mmgrid(NN, HH1), blk, 0, stream>>>(
        entb, W1a, Pent, NN, HH1, DD, nullptr, nullptr, nullptr);
    k_mfmamm<0, 0, 0, 0, 0, u16><<<mmgrid(RR, HH1), blk, 0, stream>>>(
        relb, W1a + (size_t)DD * HH1, Prel, RR, HH1, DD, nullptr, nullptr, nullptr);

    for (int v = 0; v < 2; ++v) {
        const int* ivmap  = v ? idx1 : b_x;
        const int* addidx = v ? perm : nullptr;

        // --- MCE via pull aggregation ---
        k_combine<<<wgrid(MM), blk, 0, stream>>>(ivmap, b_gi, Pent, Prel, comb, MM);
        k_pull<HH1, u16, u16><<<wgrid(MM), blk, 0, stream>>>(rpE, srcE, wE, comb, aggx, MM);
        k_mfmamm<0, 1, 0, 0, 0, u16><<<mmgrid(MM, DD), blk, 0, stream>>>(
            aggx, W1b, hb, MM, DD, HH1, nullptr, nullptr, nullptr);
        k_pull<DD, u16, u16><<<wgrid(MM), blk, 0, stream>>>(rpE, srcE, wE, hb, e_buf, MM);
        k_segpool<<<wgrid(NN), blk, 0, stream>>>(rpX, mids, e_buf, pooled, NN);
        k_mfmamm<0, 0, 0, 1, 1, u16><<<mmgrid(NN, DD), blk, 0, stream>>>(
            pooled, Wlo, ecb, NN, DD, 2 * DD, blo, entb, addidx);

        // --- DGI local ---
        k_mfmamm<0, 0, 1, 0, 0, float><<<mmgrid(NN, HIDD), blk, 0, stream>>>(
            ecb, Wg, pbuf, NN, HIDD, DD, nullptr, nullptr, nullptr);
        if (v == 0) {
            hipMemsetAsync(csum, 0, 512 * sizeof(float), stream);
            k_colsum<<<dim3((NN + 127) / 128), blk, 0, stream>>>(pbuf, csum, NN);
            k_sigc<<<dim3(1), dim3(512), 0, stream>>>(csum, cvec);
            k_tmv<<<dim3(32), dim3(64), 0, stream>>>(Wd, cvec, t_l);
        }
        k_rowdot512<<<wgrid(NN), blk, 0, stream>>>(pbuf, t_l, out + BB + (size_t)v * NN, NN);

        if (v == 0) {
            k_convkb<<<dim3(BB), blk, 0, stream>>>(ecb, relf, batch_in,
                                                   conv_w, conv_b, fc_w, fc_b, out);
        }

        // --- big GCN (f32 chain, split-MFMA) ---
        k_pull<DD, u16, float><<<wgrid(NN), blk, 0, stream>>>(rpB, srcB, wB, ecb, a1f, NN);
        k_mfmamm<1, 0, 1, 0, 0, float><<<mmgrid(NN, HH1), blk, 0, stream>>>(
            a1f, W2a, h2f, NN, HH1, DD, nullptr, nullptr, nullptr);
        k_mfmamm<1, 0, 0, 0, 0, float><<<mmgrid(NN, DD), blk, 0, stream>>>(
            h2f, W2b, h2bf, NN, DD, HH1, nullptr, nullptr, nullptr);
        k_pull<DD, float, float><<<wgrid(NN), blk, 0, stream>>>(rpB, srcB, wB, h2bf, egf, NN);

        // --- DGI global ---
        k_mfmamm<1, 0, 1, 0, 0, float><<<mmgrid(NN, HIDD), blk, 0, stream>>>(
            egf, Wg, pbuf, NN, HIDD, DD, nullptr, nullptr, nullptr);
        if (v == 0) {
            hipMemsetAsync(csum, 0, 512 * sizeof(float), stream);
            k_colsum<<<dim3((NN + 127) / 128), blk, 0, stream>>>(pbuf, csum, NN);
            k_sigc<<<dim3(1), dim3(512), 0, stream>>>(csum, cvec);
            k_tmv<<<dim3(32), dim3(64), 0, stream>>>(Wd, cvec, t_g);
        }
        k_rowdot512<<<wgrid(NN), blk, 0, stream>>>(pbuf, t_g,
                                                   out + BB + 2 * (size_t)NN + (size_t)v * NN, NN);
    }

    (void)in_sizes; (void)n_in; (void)out_size;
}

// Round 6
// 2844.410 us; speedup vs baseline: 2.3067x; 1.1148x over previous
//
#include <hip/hip_runtime.h>

#define NN   50000
#define RR   500
#define MM   120000
#define EE   960000
#define NEE  800000
#define BB   8192
#define DD   200
#define HH1  256
#define HIDD 512
#define OCC  50

typedef unsigned int  u32;
typedef unsigned short u16;
typedef __attribute__((ext_vector_type(8))) short bf16x8;
typedef __attribute__((ext_vector_type(4))) float f32x4;

static __device__ __forceinline__ float bf2f(u16 u) {
    u32 x = ((u32)u) << 16;
    return __uint_as_float(x);
}
static __device__ __forceinline__ u16 f2bf(float f) {
    u32 x = __float_as_uint(f);
    u32 r = (x + 0x7FFFu + ((x >> 16) & 1u)) >> 16;
    return (u16)r;
}
static __device__ __forceinline__ u32 pack2(float a, float b) {
    return (u32)f2bf(a) | ((u32)f2bf(b) << 16);
}
static __device__ __forceinline__ void unpack2(u32 v, float& a, float& b) {
    a = bf2f((u16)(v & 0xFFFFu));
    b = bf2f((u16)(v >> 16));
}

static __device__ __forceinline__ float wredsum(float v) {
#pragma unroll
    for (int off = 32; off > 0; off >>= 1) v += __shfl_xor(v, off);
    return v;
}

template<typename T> static __device__ __forceinline__ void stv(T* p, size_t i, float v);
template<> __device__ __forceinline__ void stv<float>(float* p, size_t i, float v) { p[i] = v; }
template<> __device__ __forceinline__ void stv<u16>(u16* p, size_t i, float v) { p[i] = f2bf(v); }

static __device__ __forceinline__ u32 relu2bf(u32 x) {
    if (x & 0x00008000u) x &= 0xFFFF0000u;
    if (x & 0x80000000u) x &= 0x0000FFFFu;
    return x;
}

// ---------------- l2 normalize rows of [rows, DD] ----------------
__global__ void k_l2norm(const float* __restrict__ in, float* __restrict__ outf,
                         u16* __restrict__ outb, int rows) {
    int w = (blockIdx.x * blockDim.x + threadIdx.x) >> 6;
    int lane = threadIdx.x & 63;
    if (w >= rows) return;
    const float* r = in + (size_t)w * DD;
    float s = 0.f;
    for (int d = lane; d < DD; d += 64) { float v = r[d]; s += v * v; }
    s = wredsum(s);
    float inv = 1.0f / fmaxf(sqrtf(s), 1e-12f);
    for (int d = lane; d < DD; d += 64) {
        float v = r[d] * inv;
        if (outf) outf[(size_t)w * DD + d] = v;
        if (outb) outb[(size_t)w * DD + d] = f2bf(v);
    }
}

__global__ void k_gather_perm(const int* __restrict__ bx, const int* __restrict__ perm,
                              int* __restrict__ idx1, int M) {
    int m = blockIdx.x * blockDim.x + threadIdx.x;
    if (m < M) idx1[m] = perm[bx[m]];
}

// edge-indexed map gather: outE[e] = map[srcE[e]]
__global__ void k_edge_idx(const int* __restrict__ srcE, const int* __restrict__ map,
                           int* __restrict__ outE, int n) {
    int e = blockIdx.x * blockDim.x + threadIdx.x;
    if (e < n) outE[e] = map[srcE[e]];
}

// ---------------- CSR build: hist + scan + fill ----------------
__global__ void k_hist(const int* __restrict__ idx, int* __restrict__ cnt, int n) {
    int i = blockIdx.x * blockDim.x + threadIdx.x;
    if (i < n) atomicAdd(&cnt[idx[i]], 1);
}

__global__ __launch_bounds__(1024) void k_scan(const int* __restrict__ in,
                                               int* __restrict__ out, int n) {
    __shared__ int wtot[16];
    __shared__ int wexc[16];
    __shared__ int s_carry;
    int tid = threadIdx.x, lane = tid & 63, wid = tid >> 6;
    if (tid == 0) s_carry = 0;
    __syncthreads();
    for (int base = 0; base < n; base += 1024) {
        int i = base + tid;
        int v = (i < n) ? in[i] : 0;
        int x = v;
#pragma unroll
        for (int off = 1; off < 64; off <<= 1) {
            int t = __shfl_up(x, off);
            if (lane >= off) x += t;
        }
        if (lane == 63) wtot[wid] = x;
        __syncthreads();
        if (wid == 0) {
            int wv2 = (lane < 16) ? wtot[lane] : 0;
            int y = wv2;
#pragma unroll
            for (int off = 1; off < 16; off <<= 1) {
                int t = __shfl_up(y, off);
                if (lane >= off) y += t;
            }
            if (lane < 16) wexc[lane] = y - wv2;
            if (lane == 15) wtot[15] = y;
        }
        __syncthreads();
        if (i < n) out[i] = s_carry + wexc[wid] + (x - v);
        int chunk_total = wtot[15];
        __syncthreads();
        if (tid == 0) s_carry += chunk_total;
        __syncthreads();
    }
    if (threadIdx.x == 0) out[n] = s_carry;
}

__global__ void k_fill2(const int* __restrict__ dst, const int* __restrict__ src,
                        const float* __restrict__ w, int* __restrict__ cursor,
                        int* __restrict__ srcs_out, float* __restrict__ ws_out, int n) {
    int e = blockIdx.x * blockDim.x + threadIdx.x;
    if (e >= n) return;
    int p = atomicAdd(&cursor[dst[e]], 1);
    srcs_out[p] = src[e];
    ws_out[p] = w[e];
}

__global__ void k_fill1(const int* __restrict__ idx, int* __restrict__ cursor,
                        int* __restrict__ outm, int n) {
    int m = blockIdx.x * blockDim.x + threadIdx.x;
    if (m >= n) return;
    int p = atomicAdd(&cursor[idx[m]], 1);
    outm[p] = m;
}

// ---------------- fused MCE pull: out[i] = sum_e w[e]*(Pent[ivE[e]] + Prel[giE[e]]) ----------------
__global__ void k_pull_mce(const int* __restrict__ rp, const int* __restrict__ ivE,
                           const int* __restrict__ giE, const float* __restrict__ wE,
                           const u16* __restrict__ Pent, const u16* __restrict__ Prel,
                           u16* __restrict__ out, int ndst) {
    int wv = (blockIdx.x * blockDim.x + threadIdx.x) >> 6;
    if (wv >= ndst) return;
    int lane = threadIdx.x & 63;
    int beg = rp[wv], end = rp[wv + 1];
    float accA[2] = {0.f, 0.f}, accB[2] = {0.f, 0.f};
    int e = beg;
    for (; e + 4 <= end; e += 4) {
        int i0 = ivE[e], i1 = ivE[e + 1], i2 = ivE[e + 2], i3 = ivE[e + 3];
        int g0 = giE[e], g1 = giE[e + 1], g2 = giE[e + 2], g3 = giE[e + 3];
        float w0 = wE[e], w1 = wE[e + 1], w2 = wE[e + 2], w3 = wE[e + 3];
        const u32* pe0 = (const u32*)(Pent + (size_t)i0 * HH1);
        const u32* pe1 = (const u32*)(Pent + (size_t)i1 * HH1);
        const u32* pe2 = (const u32*)(Pent + (size_t)i2 * HH1);
        const u32* pe3 = (const u32*)(Pent + (size_t)i3 * HH1);
        const u32* pr0 = (const u32*)(Prel + (size_t)g0 * HH1);
        const u32* pr1 = (const u32*)(Prel + (size_t)g1 * HH1);
        const u32* pr2 = (const u32*)(Prel + (size_t)g2 * HH1);
        const u32* pr3 = (const u32*)(Prel + (size_t)g3 * HH1);
        u32 vp[4][2], vr[4][2];
#pragma unroll
        for (int t = 0; t < 2; ++t) {
            int p = lane + 64 * t;
            vp[0][t] = pe0[p]; vp[1][t] = pe1[p]; vp[2][t] = pe2[p]; vp[3][t] = pe3[p];
            vr[0][t] = pr0[p]; vr[1][t] = pr1[p]; vr[2][t] = pr2[p]; vr[3][t] = pr3[p];
        }
#pragma unroll
        for (int t = 0; t < 2; ++t) {
            float a, b, c, d;
            unpack2(vp[0][t], a, b); unpack2(vr[0][t], c, d);
            accA[t] += (a + c) * w0; accB[t] += (b + d) * w0;
            unpack2(vp[1][t], a, b); unpack2(vr[1][t], c, d);
            accA[t] += (a + c) * w1; accB[t] += (b + d) * w1;
            unpack2(vp[2][t], a, b); unpack2(vr[2][t], c, d);
            accA[t] += (a + c) * w2; accB[t] += (b + d) * w2;
            unpack2(vp[3][t], a, b); unpack2(vr[3][t], c, d);
            accA[t] += (a + c) * w3; accB[t] += (b + d) * w3;
        }
    }
    for (; e < end; ++e) {
        int iv = ivE[e], gi = giE[e];
        float w = wE[e];
        const u32* pe = (const u32*)(Pent + (size_t)iv * HH1);
        const u32* pr = (const u32*)(Prel + (size_t)gi * HH1);
#pragma unroll
        for (int t = 0; t < 2; ++t) {
            int p = lane + 64 * t;
            float a, b, c, d;
            unpack2(pe[p], a, b); unpack2(pr[p], c, d);
            accA[t] += (a + c) * w; accB[t] += (b + d) * w;
        }
    }
    u32* o = (u32*)(out + (size_t)wv * HH1);
#pragma unroll
    for (int t = 0; t < 2; ++t) o[lane + 64 * t] = pack2(accA[t], accB[t]);
}

// ---------------- CSR pull (4-edge unrolled): out[i] = sum_e w[e]*in[srcs[e]] ----------------
template<int DIMS, typename TIN, typename TOUT>
__global__ void k_pull(const int* __restrict__ rp, const int* __restrict__ srcs,
                       const float* __restrict__ wsrt, const TIN* __restrict__ in,
                       TOUT* __restrict__ out, int ndst) {
    int wv = (blockIdx.x * blockDim.x + threadIdx.x) >> 6;
    if (wv >= ndst) return;
    int lane = threadIdx.x & 63;
    int beg = rp[wv], end = rp[wv + 1];
    constexpr int NP = DIMS / 2;
    constexpr int NT = (NP + 63) / 64;
    float accA[NT], accB[NT];
#pragma unroll
    for (int t = 0; t < NT; ++t) { accA[t] = 0.f; accB[t] = 0.f; }
    int e = beg;
    for (; e + 4 <= end; e += 4) {
        int s0 = srcs[e], s1 = srcs[e + 1], s2 = srcs[e + 2], s3 = srcs[e + 3];
        float w0 = wsrt[e], w1 = wsrt[e + 1], w2 = wsrt[e + 2], w3 = wsrt[e + 3];
        if constexpr (sizeof(TIN) == 2) {
            const u32* r0 = (const u32*)((const u16*)in + (size_t)s0 * DIMS);
            const u32* r1 = (const u32*)((const u16*)in + (size_t)s1 * DIMS);
            const u32* r2 = (const u32*)((const u16*)in + (size_t)s2 * DIMS);
            const u32* r3 = (const u32*)((const u16*)in + (size_t)s3 * DIMS);
            u32 v[4][NT];
#pragma unroll
            for (int t = 0; t < NT; ++t) {
                int p = lane + 64 * t;
                if (p < NP) { v[0][t] = r0[p]; v[1][t] = r1[p]; v[2][t] = r2[p]; v[3][t] = r3[p]; }
            }
#pragma unroll
            for (int t = 0; t < NT; ++t) {
                int p = lane + 64 * t;
                if (p < NP) {
                    float a, b;
                    unpack2(v[0][t], a, b); accA[t] += a * w0; accB[t] += b * w0;
                    unpack2(v[1][t], a, b); accA[t] += a * w1; accB[t] += b * w1;
                    unpack2(v[2][t], a, b); accA[t] += a * w2; accB[t] += b * w2;
                    unpack2(v[3][t], a, b); accA[t] += a * w3; accB[t] += b * w3;
                }
            }
        } else {
            const float2* r0 = (const float2*)((const float*)in + (size_t)s0 * DIMS);
            const float2* r1 = (const float2*)((const float*)in + (size_t)s1 * DIMS);
            const float2* r2 = (const float2*)((const float*)in + (size_t)s2 * DIMS);
            const float2* r3 = (const float2*)((const float*)in + (size_t)s3 * DIMS);
            float2 v[4][NT];
#pragma unroll
            for (int t = 0; t < NT; ++t) {
                int p = lane + 64 * t;
                if (p < NP) { v[0][t] = r0[p]; v[1][t] = r1[p]; v[2][t] = r2[p]; v[3][t] = r3[p]; }
            }
#pragma unroll
            for (int t = 0; t < NT; ++t) {
                int p = lane + 64 * t;
                if (p < NP) {
                    accA[t] += v[0][t].x * w0; accB[t] += v[0][t].y * w0;
                    accA[t] += v[1][t].x * w1; accB[t] += v[1][t].y * w1;
                    accA[t] += v[2][t].x * w2; accB[t] += v[2][t].y * w2;
                    accA[t] += v[3][t].x * w3; accB[t] += v[3][t].y * w3;
                }
            }
        }
    }
    for (; e < end; ++e) {
        int s = srcs[e];
        float w = wsrt[e];
        if constexpr (sizeof(TIN) == 2) {
            const u32* r = (const u32*)((const u16*)in + (size_t)s * DIMS);
#pragma unroll
            for (int t = 0; t < NT; ++t) {
                int p = lane + 64 * t;
                if (p < NP) { float a, b; unpack2(r[p], a, b); accA[t] += a * w; accB[t] += b * w; }
            }
        } else {
            const float2* r = (const float2*)((const float*)in + (size_t)s * DIMS);
#pragma unroll
            for (int t = 0; t < NT; ++t) {
                int p = lane + 64 * t;
                if (p < NP) { float2 v = r[p]; accA[t] += v.x * w; accB[t] += v.y * w; }
            }
        }
    }
    if constexpr (sizeof(TOUT) == 2) {
        u32* o = (u32*)((u16*)out + (size_t)wv * DIMS);
#pragma unroll
        for (int t = 0; t < NT; ++t) {
            int p = lane + 64 * t;
            if (p < NP) o[p] = pack2(accA[t], accB[t]);
        }
    } else {
        float2* o = (float2*)((float*)out + (size_t)wv * DIMS);
#pragma unroll
        for (int t = 0; t < NT; ++t) {
            int p = lane + 64 * t;
            if (p < NP) { float2 v; v.x = accA[t]; v.y = accB[t]; o[p] = v; }
        }
    }
}

// ---------------- fused segment mean + pooled (4-way unrolled) ----------------
__global__ void k_segpool(const int* __restrict__ rpX, const int* __restrict__ mids,
                          const u16* __restrict__ e_buf, u16* __restrict__ pooled, int n) {
    int nv = (blockIdx.x * blockDim.x + threadIdx.x) >> 6;
    if (nv >= n) return;
    int lane = threadIdx.x & 63;
    int beg = rpX[nv], end = rpX[nv + 1];
    int cnt = end - beg;
    float accA[2] = {0.f, 0.f}, accB[2] = {0.f, 0.f};
    int e = beg;
    for (; e + 4 <= end; e += 4) {
        const u32* r0 = (const u32*)(e_buf + (size_t)mids[e] * DD);
        const u32* r1 = (const u32*)(e_buf + (size_t)mids[e + 1] * DD);
        const u32* r2 = (const u32*)(e_buf + (size_t)mids[e + 2] * DD);
        const u32* r3 = (const u32*)(e_buf + (size_t)mids[e + 3] * DD);
        u32 v[4][2];
#pragma unroll
        for (int t = 0; t < 2; ++t) {
            int p = lane + 64 * t;
            if (p < DD / 2) { v[0][t] = r0[p]; v[1][t] = r1[p]; v[2][t] = r2[p]; v[3][t] = r3[p]; }
        }
#pragma unroll
        for (int t = 0; t < 2; ++t) {
            int p = lane + 64 * t;
            if (p < DD / 2) {
                float a, b;
                unpack2(v[0][t], a, b); accA[t] += a; accB[t] += b;
                unpack2(v[1][t], a, b); accA[t] += a; accB[t] += b;
                unpack2(v[2][t], a, b); accA[t] += a; accB[t] += b;
                unpack2(v[3][t], a, b); accA[t] += a; accB[t] += b;
            }
        }
    }
    for (; e < end; ++e) {
        const u32* r = (const u32*)(e_buf + (size_t)mids[e] * DD);
#pragma unroll
        for (int t = 0; t < 2; ++t) {
            int p = lane + 64 * t;
            if (p < DD / 2) { float a, b; unpack2(r[p], a, b); accA[t] += a; accB[t] += b; }
        }
    }
    float inv = 1.0f / fmaxf((float)cnt, 1.0f);
    bool occ = cnt > 0;
    const u32* er = (const u32*)(e_buf + (size_t)nv * DD);
    u32* p0 = (u32*)(pooled + (size_t)nv * (2 * DD));
#pragma unroll
    for (int t = 0; t < 2; ++t) {
        int p = lane + 64 * t;
        if (p < DD / 2) {
            p0[p] = occ ? er[p] : 0u;
            p0[DD / 2 + p] = occ ? pack2(accA[t] * inv, accB[t] * inv) : 0u;
        }
    }
}

// ---------------- MFMA matmul: C[Mr,Nc] = op(A) @ B, split-precision bf16 ----------------
template<int AMODE, int RELU_IN, int RELU_OUT, int HAS_BIAS, int HAS_ADD, typename TC>
__global__ __launch_bounds__(256) void k_mfmamm(
    const void* __restrict__ Av, const float* __restrict__ Bw, TC* __restrict__ C,
    int Mr, int Nc, int Kd,
    const float* __restrict__ bias, const u16* __restrict__ addsrc,
    const int* __restrict__ addidx) {
    constexpr int BM = 128, BN = 64, BK = 32;
    constexpr int ASTR = 40;
    __shared__ u16 Ahi[BM * ASTR];
    __shared__ u16 Alo[AMODE ? (BM * ASTR) : 8];
    __shared__ u16 Bhi[BN * ASTR];
    __shared__ u16 Blo[BN * ASTR];

    int tid = threadIdx.x;
    int wid = tid >> 6, lane = tid & 63;
    int wr = wid >> 1, wc = wid & 1;
    int r = lane & 15, h = lane >> 4;
    int bm0 = blockIdx.y * BM, bn0 = blockIdx.x * BN;

    f32x4 acc[4][2];
#pragma unroll
    for (int i = 0; i < 4; ++i)
#pragma unroll
        for (int j = 0; j < 2; ++j) acc[i][j] = (f32x4){0.f, 0.f, 0.f, 0.f};

    for (int k0 = 0; k0 < Kd; k0 += BK) {
        __syncthreads();
        {
            int row = tid >> 1, half = tid & 1;
            int gr = bm0 + row;
            int kc = k0 + half * 16;
            u16* dstA = Ahi + row * ASTR + half * 16;
            if (AMODE == 0) {
                const u16* Ab = (const u16*)Av;
                if (gr < Mr && kc + 16 <= Kd) {
                    const uint4* srcp = (const uint4*)(Ab + (size_t)gr * Kd + kc);
                    uint4 v0 = srcp[0], v1 = srcp[1];
                    if (RELU_IN) {
                        v0.x = relu2bf(v0.x); v0.y = relu2bf(v0.y);
                        v0.z = relu2bf(v0.z); v0.w = relu2bf(v0.w);
                        v1.x = relu2bf(v1.x); v1.y = relu2bf(v1.y);
                        v1.z = relu2bf(v1.z); v1.w = relu2bf(v1.w);
                    }
                    ((uint4*)dstA)[0] = v0;
                    ((uint4*)dstA)[1] = v1;
                } else {
#pragma unroll
                    for (int q = 0; q < 16; ++q) {
                        int kk = kc + q;
                        u16 u = (gr < Mr && kk < Kd) ? Ab[(size_t)gr * Kd + kk] : (u16)0;
                        if (RELU_IN && (u & 0x8000u)) u = 0;
                        dstA[q] = u;
                    }
                }
            } else {
                const float* Af = (const float*)Av;
                u16* dstL = Alo + row * ASTR + half * 16;
                if (gr < Mr && kc + 16 <= Kd) {
                    const float4* srcp = (const float4*)(Af + (size_t)gr * Kd + kc);
#pragma unroll
                    for (int s4 = 0; s4 < 4; ++s4) {
                        float4 v = srcp[s4];
                        float vs[4] = {v.x, v.y, v.z, v.w};
#pragma unroll
                        for (int q = 0; q < 4; ++q) {
                            u16 hi = f2bf(vs[q]);
                            dstA[s4 * 4 + q] = hi;
                            dstL[s4 * 4 + q] = f2bf(vs[q] - bf2f(hi));
                        }
                    }
                } else {
#pragma unroll
                    for (int q = 0; q < 16; ++q) {
                        int kk = kc + q;
                        float a = (gr < Mr && kk < Kd) ? Af[(size_t)gr * Kd + kk] : 0.f;
                        u16 hi = f2bf(a);
                        dstA[q] = hi;
                        dstL[q] = f2bf(a - bf2f(hi));
                    }
                }
            }
        }
        {
            int kb = tid >> 3;
            int nb = (tid & 7) * 8;
            int gk = k0 + kb;
#pragma unroll
            for (int q = 0; q < 8; ++q) {
                int gn = bn0 + nb + q;
                float b = (gk < Kd && gn < Nc) ? Bw[(size_t)gk * Nc + gn] : 0.f;
                u16 hi = f2bf(b);
                Bhi[(nb + q) * ASTR + kb] = hi;
                Blo[(nb + q) * ASTR + kb] = f2bf(b - bf2f(hi));
            }
        }
        __syncthreads();
        bf16x8 af[4], al[4], bh[2], bl[2];
#pragma unroll
        for (int j = 0; j < 2; ++j) {
            int nrow = wc * 32 + j * 16 + r;
            bh[j] = *(const bf16x8*)(Bhi + nrow * ASTR + h * 8);
            bl[j] = *(const bf16x8*)(Blo + nrow * ASTR + h * 8);
        }
#pragma unroll
        for (int i = 0; i < 4; ++i) {
            int mrow = wr * 64 + i * 16 + r;
            af[i] = *(const bf16x8*)(Ahi + mrow * ASTR + h * 8);
            if (AMODE) al[i] = *(const bf16x8*)(Alo + mrow * ASTR + h * 8);
        }
#pragma unroll
        for (int i = 0; i < 4; ++i)
#pragma unroll
            for (int j = 0; j < 2; ++j) {
                acc[i][j] = __builtin_amdgcn_mfma_f32_16x16x32_bf16(af[i], bh[j], acc[i][j], 0, 0, 0);
                acc[i][j] = __builtin_amdgcn_mfma_f32_16x16x32_bf16(af[i], bl[j], acc[i][j], 0, 0, 0);
                if (AMODE)
                    acc[i][j] = __builtin_amdgcn_mfma_f32_16x16x32_bf16(al[i], bh[j], acc[i][j], 0, 0, 0);
            }
    }
#pragma unroll
    for (int i = 0; i < 4; ++i) {
#pragma unroll
        for (int j = 0; j < 2; ++j) {
            int col = bn0 + wc * 32 + j * 16 + r;
            if (col >= Nc) continue;
            int rowb = bm0 + wr * 64 + i * 16 + h * 4;
#pragma unroll
            for (int rg = 0; rg < 4; ++rg) {
                int row = rowb + rg;
                if (row >= Mr) continue;
                float v = acc[i][j][rg];
                if (HAS_BIAS) v += bias[col];
                if (RELU_OUT) v = fmaxf(v, 0.f);
                if (HAS_ADD) {
                    int r2 = addidx ? addidx[row] : row;
                    v += bf2f(addsrc[(size_t)r2 * Nc + col]);
                }
                stv(C, (size_t)row * Nc + col, v);
            }
        }
    }
}

// ---------------- DGI helpers (f32 p-buffer) ----------------
__global__ void k_colsum(const float* __restrict__ p, float* __restrict__ csum, int rows) {
    int c2 = threadIdx.x;
    int r0 = blockIdx.x * 128;
    int rend = min(r0 + 128, rows);
    float s0 = 0.f, s1 = 0.f;
    for (int r = r0; r < rend; ++r) {
        s0 += p[(size_t)r * HIDD + c2 * 2];
        s1 += p[(size_t)r * HIDD + c2 * 2 + 1];
    }
    atomicAdd(&csum[c2 * 2], s0);
    atomicAdd(&csum[c2 * 2 + 1], s1);
}

__global__ void k_sigc(const float* __restrict__ csum, float* __restrict__ cvec) {
    int i = threadIdx.x;
    cvec[i] = 1.0f / (1.0f + expf(-csum[i] * (1.0f / (float)NN)));
}

__global__ void k_tmv(const float* __restrict__ Wd, const float* __restrict__ cvec,
                      float* __restrict__ tvec) {
    __shared__ float c[HIDD];
    int lane = threadIdx.x;
    for (int j = lane; j < HIDD; j += 64) c[j] = cvec[j];
    __syncthreads();
    int r0 = blockIdx.x * 16;
    for (int i = r0; i < r0 + 16; ++i) {
        const float* wr = Wd + (size_t)i * HIDD;
        float s = 0.f;
        for (int j = lane; j < HIDD; j += 64) s += wr[j] * c[j];
        s = wredsum(s);
        if (lane == 0) tvec[i] = s;
    }
}

__global__ void k_rowdot512(const float* __restrict__ p, const float* __restrict__ t,
                            float* __restrict__ out, int rows) {
    int g = blockIdx.x * blockDim.x + threadIdx.x;
    int wv = g >> 6;
    if (wv >= rows) return;
    int lane = g & 63;
    const float* r = p + (size_t)wv * HIDD;
    float s = 0.f;
#pragma unroll
    for (int t4 = 0; t4 < 8; ++t4) {
        int d = lane + t4 * 64;
        s += r[d] * t[d];
    }
    s = wredsum(s);
    if (lane == 0) out[wv] = s;
}

// ---------------- ConvKB ----------------
__global__ void k_convkb(const u16* __restrict__ ec, const float* __restrict__ rel,
                         const int* __restrict__ bi, const float* __restrict__ cw,
                         const float* __restrict__ cb, const float* __restrict__ fcw,
                         const float* __restrict__ fcb, float* __restrict__ out) {
    __shared__ float t0[DD], t1[DD], t2[DD];
    __shared__ float red[4];
    int b = blockIdx.x, tid = threadIdx.x;
    int i0 = bi[b * 3 + 0], i1 = bi[b * 3 + 1], i2 = bi[b * 3 + 2];
    if (tid < DD) {
        t0[tid] = bf2f(ec[(size_t)i0 * DD + tid]);
        t1[tid] = rel[(size_t)i1 * DD + tid];
        t2[tid] = bf2f(ec[(size_t)i2 * DD + tid]);
    }
    __syncthreads();
    float partial = 0.f;
    if (tid < DD) {
        float a = t0[tid], bb = t1[tid], c = t2[tid];
        for (int o = 0; o < OCC; ++o) {
            float h = fmaxf(cw[o * 3 + 0] * a + cw[o * 3 + 1] * bb + cw[o * 3 + 2] * c + cb[o], 0.f);
            partial += h * fcw[o * DD + tid];
        }
    }
    partial = wredsum(partial);
    if ((tid & 63) == 0) red[tid >> 6] = partial;
    __syncthreads();
    if (tid == 0) out[b] = red[0] + red[1] + red[2] + red[3] + fcb[0];
}

__global__ void k_sentinel(float* out, float val) { out[threadIdx.x] = val; }

extern "C" void kernel_launch(void* const* d_in, const int* in_sizes, int n_in,
                              void* d_out, int out_size, void* d_ws, size_t ws_size,
                              hipStream_t stream) {
    const float* entity_emb = (const float*)d_in[0];
    const float* rel_emb    = (const float*)d_in[1];
    const int*   b_x        = (const int*)d_in[2];
    const int*   b_gi       = (const int*)d_in[3];
    const int*   e_src      = (const int*)d_in[4];
    const int*   e_dst      = (const int*)d_in[5];
    const float* e_w        = (const float*)d_in[6];
    const int*   big_src    = (const int*)d_in[7];
    const int*   big_dst    = (const int*)d_in[8];
    const float* big_w      = (const float*)d_in[9];
    const int*   perm       = (const int*)d_in[10];
    const int*   batch_in   = (const int*)d_in[11];
    const float* W1a        = (const float*)d_in[12];
    const float* W1b        = (const float*)d_in[13];
    const float* W2a        = (const float*)d_in[14];
    const float* W2b        = (const float*)d_in[15];
    // Wle/ble unused: segment softmax weights sum to exactly 1 and every row in a
    // segment shares the same emb vector -> pooled[n] == occ(n)*concat(e[n],mean[n])
    const float* Wlo        = (const float*)d_in[18];
    const float* blo        = (const float*)d_in[19];
    const float* Wg         = (const float*)d_in[20];
    const float* Wd         = (const float*)d_in[21];
    const float* conv_w     = (const float*)d_in[22];
    const float* conv_b     = (const float*)d_in[23];
    const float* fc_w       = (const float*)d_in[24];
    const float* fc_b       = (const float*)d_in[25];
    float* out = (float*)d_out;

    size_t off = 0;
    auto balloc = [&](size_t nbytes) {
        size_t p = off;
        off += (nbytes + 511) & ~(size_t)511;
        return p;
    };
    char* base = (char*)d_ws;
    u16*   entb = (u16*)(base + balloc((size_t)NN * DD * 2));
    float* relf = (float*)(base + balloc((size_t)RR * DD * 4));
    u16*   relb = (u16*)(base + balloc((size_t)RR * DD * 2));
    u16*   Pent = (u16*)(base + balloc((size_t)NN * HH1 * 2));
    u16*   Prel = (u16*)(base + balloc((size_t)RR * HH1 * 2));
    int*   idx1 = (int*)(base + balloc((size_t)MM * 4));
    u16*   ecb  = (u16*)(base + balloc((size_t)NN * DD * 2));
    int*   rpB  = (int*)(base + balloc((size_t)(NN + 1) * 4));
    int*   srcB = (int*)(base + balloc((size_t)NEE * 4));
    float* wB   = (float*)(base + balloc((size_t)NEE * 4));
    int*   rpE  = (int*)(base + balloc((size_t)(MM + 1) * 4));
    int*   srcE = (int*)(base + balloc((size_t)EE * 4));
    float* wE   = (float*)(base + balloc((size_t)EE * 4));
    int*   ivE  = (int*)(base + balloc((size_t)EE * 4));
    int*   giE  = (int*)(base + balloc((size_t)EE * 4));
    int*   rpX  = (int*)(base + balloc((size_t)(NN + 1) * 4));
    int*   mids = (int*)(base + balloc((size_t)MM * 4));
    int*   curB = (int*)(base + balloc((size_t)NN * 4));
    int*   curE = (int*)(base + balloc((size_t)MM * 4));
    int*   curX = (int*)(base + balloc((size_t)NN * 4));
    char*  Aarena = base + balloc((size_t)MM * HH1 * 2);   // 61.44 MB
    char*  Barena = base + balloc((size_t)MM * DD * 2);    // 48 MB
    char*  Carena = base + balloc((size_t)MM * DD * 2);    // 48 MB
    float* csum = (float*)(base + balloc(4 * 2048));
    float* cvec = csum + 512;
    float* t_l  = csum + 1024;
    float* t_g  = csum + 1536;

    if (ws_size < off) {
        k_sentinel<<<dim3(1), dim3(8), 0, stream>>>(out, (float)(ws_size >> 20));
        return;
    }

    u16*   aggx   = (u16*)Aarena;                 // [MM,256] bf16
    u16*   hb     = (u16*)Barena;                 // [MM,200] bf16
    u16*   e_buf  = (u16*)Carena;                 // [MM,200] bf16
    u16*   pooled = (u16*)Aarena;                 // [NN,400] bf16 (aggx dead)
    float* a1f    = (float*)Aarena;               // [NN,200] f32
    float* h2f    = (float*)Barena;               // [NN,256] f32 (spans B..C)
    float* h2bf   = (float*)Aarena;               // [NN,200] f32
    float* egf    = (float*)Carena;               // [NN,200] f32
    float* pbuf   = (float*)Aarena;               // [NN,512] f32 (spans A..B)

    dim3 blk(256);
    auto wgrid = [](int items) { return dim3((unsigned)((items + 3) / 4)); };
    auto tgrid = [](int items) { return dim3((unsigned)((items + 255) / 256)); };
    auto mmgrid = [](int Mr, int Nc) { return dim3((unsigned)((Nc + 63) / 64), (unsigned)((Mr + 127) / 128)); };

    // ---- normalize + perm gather ----
    k_l2norm<<<wgrid(NN), blk, 0, stream>>>(entity_emb, nullptr, entb, NN);
    k_l2norm<<<wgrid(RR), blk, 0, stream>>>(rel_emb, relf, relb, RR);
    k_gather_perm<<<tgrid(MM), blk, 0, stream>>>(b_x, perm, idx1, MM);

    // ---- CSR builds ----
    hipMemsetAsync(curB, 0, (size_t)NN * 4, stream);
    hipMemsetAsync(curE, 0, (size_t)MM * 4, stream);
    hipMemsetAsync(curX, 0, (size_t)NN * 4, stream);
    k_hist<<<tgrid(NEE), blk, 0, stream>>>(big_dst, curB, NEE);
    k_hist<<<tgrid(EE), blk, 0, stream>>>(e_dst, curE, EE);
    k_hist<<<tgrid(MM), blk, 0, stream>>>(b_x, curX, MM);
    k_scan<<<dim3(1), dim3(1024), 0, stream>>>(curB, rpB, NN);
    k_scan<<<dim3(1), dim3(1024), 0, stream>>>(curE, rpE, MM);
    k_scan<<<dim3(1), dim3(1024), 0, stream>>>(curX, rpX, NN);
    hipMemcpyAsync(curB, rpB, (size_t)NN * 4, hipMemcpyDeviceToDevice, stream);
    hipMemcpyAsync(curE, rpE, (size_t)MM * 4, hipMemcpyDeviceToDevice, stream);
    hipMemcpyAsync(curX, rpX, (size_t)NN * 4, hipMemcpyDeviceToDevice, stream);
    k_fill2<<<tgrid(NEE), blk, 0, stream>>>(big_dst, big_src, big_w, curB, srcB, wB, NEE);
    k_fill2<<<tgrid(EE), blk, 0, stream>>>(e_dst, e_src, e_w, curE, srcE, wE, EE);
    k_fill1<<<tgrid(MM), blk, 0, stream>>>(b_x, curX, mids, MM);
    // per-edge graph index (fixed across passes)
    k_edge_idx<<<tgrid(EE), blk, 0, stream>>>(srcE, b_gi, giE, EE);

    // ---- P_ent = ent @ W1a[:200], P_rel = rel @ W1a[200:] ----
    k_mfmamm<0, 0, 0, 0, 0, u16><<<mmgrid(NN, HH1), blk, 0, stream>>>(
        entb, W1a, Pent, NN, HH1, DD, nullptr, nullptr, nullptr);
    k_mfmamm<0, 0, 0, 0, 0, u16><<<mmgrid(RR, HH1), blk, 0, stream>>>(
        relb, W1a + (size_t)DD * HH1, Prel, RR, HH1, DD, nullptr, nullptr, nullptr);

    for (int v = 0; v < 2; ++v) {
        const int* ivmap  = v ? idx1 : b_x;
        const int* addidx = v ? perm : nullptr;

        // --- MCE via fused pull aggregation (gathers Pent/Prel directly) ---
        k_edge_idx<<<tgrid(EE), blk, 0, stream>>>(srcE, ivmap, ivE, EE);
        k_pull_mce<<<wgrid(MM), blk, 0, stream>>>(rpE, ivE, giE, wE, Pent, Prel, aggx, MM);
        k_mfmamm<0, 1, 0, 0, 0, u16><<<mmgrid(MM, DD), blk, 0, stream>>>(
            aggx, W1b, hb, MM, DD, HH1, nullptr, nullptr, nullptr);
        k_pull<DD, u16, u16><<<wgrid(MM), blk, 0, stream>>>(rpE, srcE, wE, hb, e_buf, MM);
        k_segpool<<<wgrid(NN), blk, 0, stream>>>(rpX, mids, e_buf, pooled, NN);
        k_mfmamm<0, 0, 0, 1, 1, u16><<<mmgrid(NN, DD), blk, 0, stream>>>(
            pooled, Wlo, ecb, NN, DD, 2 * DD, blo, entb, addidx);

        // --- DGI local ---
        k_mfmamm<0, 0, 1, 0, 0, float><<<mmgrid(NN, HIDD), blk, 0, stream>>>(
            ecb, Wg, pbuf, NN, HIDD, DD, nullptr, nullptr, nullptr);
        if (v == 0) {
            hipMemsetAsync(csum, 0, 512 * sizeof(float), stream);
            k_colsum<<<dim3((NN + 127) / 128), blk, 0, stream>>>(pbuf, csum, NN);
            k_sigc<<<dim3(1), dim3(512), 0, stream>>>(csum, cvec);
            k_tmv<<<dim3(32), dim3(64), 0, stream>>>(Wd, cvec, t_l);
        }
        k_rowdot512<<<wgrid(NN), blk, 0, stream>>>(pbuf, t_l, out + BB + (size_t)v * NN, NN);

        if (v == 0) {
            k_convkb<<<dim3(BB), blk, 0, stream>>>(ecb, relf, batch_in,
                                                   conv_w, conv_b, fc_w, fc_b, out);
        }

        // --- big GCN (f32 chain, split-MFMA) ---
        k_pull<DD, u16, float><<<wgrid(NN), blk, 0, stream>>>(rpB, srcB, wB, ecb, a1f, NN);
        k_mfmamm<1, 0, 1, 0, 0, float><<<mmgrid(NN, HH1), blk, 0, stream>>>(
            a1f, W2a, h2f, NN, HH1, DD, nullptr, nullptr, nullptr);
        k_mfmamm<1, 0, 0, 0, 0, float><<<mmgrid(NN, DD), blk, 0, stream>>>(
            h2f, W2b, h2bf, NN, DD, HH1, nullptr, nullptr, nullptr);
        k_pull<DD, float, float><<<wgrid(NN), blk, 0, stream>>>(rpB, srcB, wB, h2bf, egf, NN);

        // --- DGI global ---
        k_mfmamm<1, 0, 1, 0, 0, float><<<mmgrid(NN, HIDD), blk, 0, stream>>>(
            egf, Wg, pbuf, NN, HIDD, DD, nullptr, nullptr, nullptr);
        if (v == 0) {
            hipMemsetAsync(csum, 0, 512 * sizeof(float), stream);
            k_colsum<<<dim3((NN + 127) / 128), blk, 0, stream>>>(pbuf, csum, NN);
            k_sigc<<<dim3(1), dim3(512), 0, stream>>>(csum, cvec);
            k_tmv<<<dim3(32), dim3(64), 0, stream>>>(Wd, cvec, t_g);
        }
        k_rowdot512<<<wgrid(NN), blk, 0, stream>>>(pbuf, t_g,
                                                   out + BB + 2 * (size_t)NN + (size_t)v * NN, NN);
    }

    (void)in_sizes; (void)n_in; (void)out_size;
}

// Round 7
// 2313.919 us; speedup vs baseline: 2.8356x; 1.2293x over previous
//
#include <hip/hip_runtime.h>

#define NN   50000
#define RR   500
#define MM   120000
#define EE   960000
#define NEE  800000
#define BB   8192
#define DD   200
#define HH1  256
#define HIDD 512
#define OCC  50

typedef unsigned int  u32;
typedef unsigned short u16;
typedef __attribute__((ext_vector_type(8))) short bf16x8;
typedef __attribute__((ext_vector_type(4))) float f32x4;

static __device__ __forceinline__ float bf2f(u16 u) {
    u32 x = ((u32)u) << 16;
    return __uint_as_float(x);
}
static __device__ __forceinline__ u16 f2bf(float f) {
    u32 x = __float_as_uint(f);
    u32 r = (x + 0x7FFFu + ((x >> 16) & 1u)) >> 16;
    return (u16)r;
}
static __device__ __forceinline__ u32 pack2(float a, float b) {
    return (u32)f2bf(a) | ((u32)f2bf(b) << 16);
}
static __device__ __forceinline__ void unpack2(u32 v, float& a, float& b) {
    a = bf2f((u16)(v & 0xFFFFu));
    b = bf2f((u16)(v >> 16));
}

static __device__ __forceinline__ float wredsum(float v) {
#pragma unroll
    for (int off = 32; off > 0; off >>= 1) v += __shfl_xor(v, off);
    return v;
}

template<typename T> static __device__ __forceinline__ void stv(T* p, size_t i, float v);
template<> __device__ __forceinline__ void stv<float>(float* p, size_t i, float v) { p[i] = v; }
template<> __device__ __forceinline__ void stv<u16>(u16* p, size_t i, float v) { p[i] = f2bf(v); }

static __device__ __forceinline__ u32 relu2bf(u32 x) {
    if (x & 0x00008000u) x &= 0xFFFF0000u;
    if (x & 0x80000000u) x &= 0x0000FFFFu;
    return x;
}

// ---------------- l2 normalize rows of [rows, DD] ----------------
__global__ void k_l2norm(const float* __restrict__ in, float* __restrict__ outf,
                         u16* __restrict__ outb, int rows) {
    int w = (blockIdx.x * blockDim.x + threadIdx.x) >> 6;
    int lane = threadIdx.x & 63;
    if (w >= rows) return;
    const float* r = in + (size_t)w * DD;
    float s = 0.f;
    for (int d = lane; d < DD; d += 64) { float v = r[d]; s += v * v; }
    s = wredsum(s);
    float inv = 1.0f / fmaxf(sqrtf(s), 1e-12f);
    for (int d = lane; d < DD; d += 64) {
        float v = r[d] * inv;
        if (outf) outf[(size_t)w * DD + d] = v;
        if (outb) outb[(size_t)w * DD + d] = f2bf(v);
    }
}

__global__ void k_gather_perm(const int* __restrict__ bx, const int* __restrict__ perm,
                              int* __restrict__ idx1, int M) {
    int m = blockIdx.x * blockDim.x + threadIdx.x;
    if (m < M) idx1[m] = perm[bx[m]];
}

// edge-indexed map gather: outE[e] = map[srcE[e]]
__global__ void k_edge_idx(const int* __restrict__ srcE, const int* __restrict__ map,
                           int* __restrict__ outE, int n) {
    int e = blockIdx.x * blockDim.x + threadIdx.x;
    if (e < n) outE[e] = map[srcE[e]];
}

// ---------------- CSR build: hist + scan + fill ----------------
__global__ void k_hist(const int* __restrict__ idx, int* __restrict__ cnt, int n) {
    int i = blockIdx.x * blockDim.x + threadIdx.x;
    if (i < n) atomicAdd(&cnt[idx[i]], 1);
}

__global__ __launch_bounds__(1024) void k_scan(const int* __restrict__ in,
                                               int* __restrict__ out, int n) {
    __shared__ int wtot[16];
    __shared__ int wexc[16];
    __shared__ int s_carry;
    int tid = threadIdx.x, lane = tid & 63, wid = tid >> 6;
    if (tid == 0) s_carry = 0;
    __syncthreads();
    for (int base = 0; base < n; base += 1024) {
        int i = base + tid;
        int v = (i < n) ? in[i] : 0;
        int x = v;
#pragma unroll
        for (int off = 1; off < 64; off <<= 1) {
            int t = __shfl_up(x, off);
            if (lane >= off) x += t;
        }
        if (lane == 63) wtot[wid] = x;
        __syncthreads();
        if (wid == 0) {
            int wv2 = (lane < 16) ? wtot[lane] : 0;
            int y = wv2;
#pragma unroll
            for (int off = 1; off < 16; off <<= 1) {
                int t = __shfl_up(y, off);
                if (lane >= off) y += t;
            }
            if (lane < 16) wexc[lane] = y - wv2;
            if (lane == 15) wtot[15] = y;
        }
        __syncthreads();
        if (i < n) out[i] = s_carry + wexc[wid] + (x - v);
        int chunk_total = wtot[15];
        __syncthreads();
        if (tid == 0) s_carry += chunk_total;
        __syncthreads();
    }
    if (threadIdx.x == 0) out[n] = s_carry;
}

__global__ void k_fill2(const int* __restrict__ dst, const int* __restrict__ src,
                        const float* __restrict__ w, int* __restrict__ cursor,
                        int* __restrict__ srcs_out, float* __restrict__ ws_out, int n) {
    int e = blockIdx.x * blockDim.x + threadIdx.x;
    if (e >= n) return;
    int p = atomicAdd(&cursor[dst[e]], 1);
    srcs_out[p] = src[e];
    ws_out[p] = w[e];
}

__global__ void k_fill1(const int* __restrict__ idx, int* __restrict__ cursor,
                        int* __restrict__ outm, int n) {
    int m = blockIdx.x * blockDim.x + threadIdx.x;
    if (m >= n) return;
    int p = atomicAdd(&cursor[idx[m]], 1);
    outm[p] = m;
}

// ---------------- fused MCE pull: out[i] = sum_e w[e]*(Pent[ivE[e]] + Prel[giE[e]]) ----------------
__global__ void k_pull_mce(const int* __restrict__ rp, const int* __restrict__ ivE,
                           const int* __restrict__ giE, const float* __restrict__ wE,
                           const u16* __restrict__ Pent, const u16* __restrict__ Prel,
                           u16* __restrict__ out, int ndst) {
    int wv = (blockIdx.x * blockDim.x + threadIdx.x) >> 6;
    if (wv >= ndst) return;
    int lane = threadIdx.x & 63;
    int beg = rp[wv], end = rp[wv + 1];
    float accA[2] = {0.f, 0.f}, accB[2] = {0.f, 0.f};
    int e = beg;
    for (; e + 4 <= end; e += 4) {
        int i0 = ivE[e], i1 = ivE[e + 1], i2 = ivE[e + 2], i3 = ivE[e + 3];
        int g0 = giE[e], g1 = giE[e + 1], g2 = giE[e + 2], g3 = giE[e + 3];
        float w0 = wE[e], w1 = wE[e + 1], w2 = wE[e + 2], w3 = wE[e + 3];
        const u32* pe0 = (const u32*)(Pent + (size_t)i0 * HH1);
        const u32* pe1 = (const u32*)(Pent + (size_t)i1 * HH1);
        const u32* pe2 = (const u32*)(Pent + (size_t)i2 * HH1);
        const u32* pe3 = (const u32*)(Pent + (size_t)i3 * HH1);
        const u32* pr0 = (const u32*)(Prel + (size_t)g0 * HH1);
        const u32* pr1 = (const u32*)(Prel + (size_t)g1 * HH1);
        const u32* pr2 = (const u32*)(Prel + (size_t)g2 * HH1);
        const u32* pr3 = (const u32*)(Prel + (size_t)g3 * HH1);
        u32 vp[4][2], vr[4][2];
#pragma unroll
        for (int t = 0; t < 2; ++t) {
            int p = lane + 64 * t;
            vp[0][t] = pe0[p]; vp[1][t] = pe1[p]; vp[2][t] = pe2[p]; vp[3][t] = pe3[p];
            vr[0][t] = pr0[p]; vr[1][t] = pr1[p]; vr[2][t] = pr2[p]; vr[3][t] = pr3[p];
        }
#pragma unroll
        for (int t = 0; t < 2; ++t) {
            float a, b, c, d;
            unpack2(vp[0][t], a, b); unpack2(vr[0][t], c, d);
            accA[t] += (a + c) * w0; accB[t] += (b + d) * w0;
            unpack2(vp[1][t], a, b); unpack2(vr[1][t], c, d);
            accA[t] += (a + c) * w1; accB[t] += (b + d) * w1;
            unpack2(vp[2][t], a, b); unpack2(vr[2][t], c, d);
            accA[t] += (a + c) * w2; accB[t] += (b + d) * w2;
            unpack2(vp[3][t], a, b); unpack2(vr[3][t], c, d);
            accA[t] += (a + c) * w3; accB[t] += (b + d) * w3;
        }
    }
    for (; e < end; ++e) {
        int iv = ivE[e], gi = giE[e];
        float w = wE[e];
        const u32* pe = (const u32*)(Pent + (size_t)iv * HH1);
        const u32* pr = (const u32*)(Prel + (size_t)gi * HH1);
#pragma unroll
        for (int t = 0; t < 2; ++t) {
            int p = lane + 64 * t;
            float a, b, c, d;
            unpack2(pe[p], a, b); unpack2(pr[p], c, d);
            accA[t] += (a + c) * w; accB[t] += (b + d) * w;
        }
    }
    u32* o = (u32*)(out + (size_t)wv * HH1);
#pragma unroll
    for (int t = 0; t < 2; ++t) o[lane + 64 * t] = pack2(accA[t], accB[t]);
}

// ---------------- CSR pull (4-edge unrolled): out[i] = sum_e w[e]*in[srcs[e]] ----------------
template<int DIMS, typename TIN, typename TOUT>
__global__ void k_pull(const int* __restrict__ rp, const int* __restrict__ srcs,
                       const float* __restrict__ wsrt, const TIN* __restrict__ in,
                       TOUT* __restrict__ out, int ndst) {
    int wv = (blockIdx.x * blockDim.x + threadIdx.x) >> 6;
    if (wv >= ndst) return;
    int lane = threadIdx.x & 63;
    int beg = rp[wv], end = rp[wv + 1];
    constexpr int NP = DIMS / 2;
    constexpr int NT = (NP + 63) / 64;
    float accA[NT], accB[NT];
#pragma unroll
    for (int t = 0; t < NT; ++t) { accA[t] = 0.f; accB[t] = 0.f; }
    int e = beg;
    for (; e + 4 <= end; e += 4) {
        int s0 = srcs[e], s1 = srcs[e + 1], s2 = srcs[e + 2], s3 = srcs[e + 3];
        float w0 = wsrt[e], w1 = wsrt[e + 1], w2 = wsrt[e + 2], w3 = wsrt[e + 3];
        if constexpr (sizeof(TIN) == 2) {
            const u32* r0 = (const u32*)((const u16*)in + (size_t)s0 * DIMS);
            const u32* r1 = (const u32*)((const u16*)in + (size_t)s1 * DIMS);
            const u32* r2 = (const u32*)((const u16*)in + (size_t)s2 * DIMS);
            const u32* r3 = (const u32*)((const u16*)in + (size_t)s3 * DIMS);
            u32 v[4][NT];
#pragma unroll
            for (int t = 0; t < NT; ++t) {
                int p = lane + 64 * t;
                if (p < NP) { v[0][t] = r0[p]; v[1][t] = r1[p]; v[2][t] = r2[p]; v[3][t] = r3[p]; }
            }
#pragma unroll
            for (int t = 0; t < NT; ++t) {
                int p = lane + 64 * t;
                if (p < NP) {
                    float a, b;
                    unpack2(v[0][t], a, b); accA[t] += a * w0; accB[t] += b * w0;
                    unpack2(v[1][t], a, b); accA[t] += a * w1; accB[t] += b * w1;
                    unpack2(v[2][t], a, b); accA[t] += a * w2; accB[t] += b * w2;
                    unpack2(v[3][t], a, b); accA[t] += a * w3; accB[t] += b * w3;
                }
            }
        } else {
            const float2* r0 = (const float2*)((const float*)in + (size_t)s0 * DIMS);
            const float2* r1 = (const float2*)((const float*)in + (size_t)s1 * DIMS);
            const float2* r2 = (const float2*)((const float*)in + (size_t)s2 * DIMS);
            const float2* r3 = (const float2*)((const float*)in + (size_t)s3 * DIMS);
            float2 v[4][NT];
#pragma unroll
            for (int t = 0; t < NT; ++t) {
                int p = lane + 64 * t;
                if (p < NP) { v[0][t] = r0[p]; v[1][t] = r1[p]; v[2][t] = r2[p]; v[3][t] = r3[p]; }
            }
#pragma unroll
            for (int t = 0; t < NT; ++t) {
                int p = lane + 64 * t;
                if (p < NP) {
                    accA[t] += v[0][t].x * w0; accB[t] += v[0][t].y * w0;
                    accA[t] += v[1][t].x * w1; accB[t] += v[1][t].y * w1;
                    accA[t] += v[2][t].x * w2; accB[t] += v[2][t].y * w2;
                    accA[t] += v[3][t].x * w3; accB[t] += v[3][t].y * w3;
                }
            }
        }
    }
    for (; e < end; ++e) {
        int s = srcs[e];
        float w = wsrt[e];
        if constexpr (sizeof(TIN) == 2) {
            const u32* r = (const u32*)((const u16*)in + (size_t)s * DIMS);
#pragma unroll
            for (int t = 0; t < NT; ++t) {
                int p = lane + 64 * t;
                if (p < NP) { float a, b; unpack2(r[p], a, b); accA[t] += a * w; accB[t] += b * w; }
            }
        } else {
            const float2* r = (const float2*)((const float*)in + (size_t)s * DIMS);
#pragma unroll
            for (int t = 0; t < NT; ++t) {
                int p = lane + 64 * t;
                if (p < NP) { float2 v = r[p]; accA[t] += v.x * w; accB[t] += v.y * w; }
            }
        }
    }
    if constexpr (sizeof(TOUT) == 2) {
        u32* o = (u32*)((u16*)out + (size_t)wv * DIMS);
#pragma unroll
        for (int t = 0; t < NT; ++t) {
            int p = lane + 64 * t;
            if (p < NP) o[p] = pack2(accA[t], accB[t]);
        }
    } else {
        float2* o = (float2*)((float*)out + (size_t)wv * DIMS);
#pragma unroll
        for (int t = 0; t < NT; ++t) {
            int p = lane + 64 * t;
            if (p < NP) { float2 v; v.x = accA[t]; v.y = accB[t]; o[p] = v; }
        }
    }
}

// ---------------- fused segment mean + pooled (4-way unrolled) ----------------
__global__ void k_segpool(const int* __restrict__ rpX, const int* __restrict__ mids,
                          const u16* __restrict__ e_buf, u16* __restrict__ pooled, int n) {
    int nv = (blockIdx.x * blockDim.x + threadIdx.x) >> 6;
    if (nv >= n) return;
    int lane = threadIdx.x & 63;
    int beg = rpX[nv], end = rpX[nv + 1];
    int cnt = end - beg;
    float accA[2] = {0.f, 0.f}, accB[2] = {0.f, 0.f};
    int e = beg;
    for (; e + 4 <= end; e += 4) {
        const u32* r0 = (const u32*)(e_buf + (size_t)mids[e] * DD);
        const u32* r1 = (const u32*)(e_buf + (size_t)mids[e + 1] * DD);
        const u32* r2 = (const u32*)(e_buf + (size_t)mids[e + 2] * DD);
        const u32* r3 = (const u32*)(e_buf + (size_t)mids[e + 3] * DD);
        u32 v[4][2];
#pragma unroll
        for (int t = 0; t < 2; ++t) {
            int p = lane + 64 * t;
            if (p < DD / 2) { v[0][t] = r0[p]; v[1][t] = r1[p]; v[2][t] = r2[p]; v[3][t] = r3[p]; }
        }
#pragma unroll
        for (int t = 0; t < 2; ++t) {
            int p = lane + 64 * t;
            if (p < DD / 2) {
                float a, b;
                unpack2(v[0][t], a, b); accA[t] += a; accB[t] += b;
                unpack2(v[1][t], a, b); accA[t] += a; accB[t] += b;
                unpack2(v[2][t], a, b); accA[t] += a; accB[t] += b;
                unpack2(v[3][t], a, b); accA[t] += a; accB[t] += b;
            }
        }
    }
    for (; e < end; ++e) {
        const u32* r = (const u32*)(e_buf + (size_t)mids[e] * DD);
#pragma unroll
        for (int t = 0; t < 2; ++t) {
            int p = lane + 64 * t;
            if (p < DD / 2) { float a, b; unpack2(r[p], a, b); accA[t] += a; accB[t] += b; }
        }
    }
    float inv = 1.0f / fmaxf((float)cnt, 1.0f);
    bool occ = cnt > 0;
    const u32* er = (const u32*)(e_buf + (size_t)nv * DD);
    u32* p0 = (u32*)(pooled + (size_t)nv * (2 * DD));
#pragma unroll
    for (int t = 0; t < 2; ++t) {
        int p = lane + 64 * t;
        if (p < DD / 2) {
            p0[p] = occ ? er[p] : 0u;
            p0[DD / 2 + p] = occ ? pack2(accA[t] * inv, accB[t] * inv) : 0u;
        }
    }
}

// ---------------- MFMA matmul: C[Mr,Nc] = op(A) @ B, split-precision bf16 ----------------
// AMODE 0: A bf16, B split hi+lo (2 MFMA); AMODE 1: A f32 split, B hi (3 MFMA)
// FUSE 0: none; 1: write C + atomic column-sum into redout; 2: no C write, atomic row-dot(tvec) into redout
template<int AMODE, int RELU_IN, int RELU_OUT, int HAS_BIAS, int HAS_ADD, int FUSE, typename TC>
__global__ __launch_bounds__(256, 2) void k_mfmamm(
    const void* __restrict__ Av, const float* __restrict__ Bw, TC* __restrict__ C,
    int Mr, int Nc, int Kd,
    const float* __restrict__ bias, const u16* __restrict__ addsrc,
    const int* __restrict__ addidx, const float* __restrict__ tvec,
    float* __restrict__ redout) {
    constexpr int BM = 128, BN = 128, BK = 32;
    constexpr int ASTR = 40;  // u16 units: 80B rows, 16B-aligned, bank period 8 (2-way = free)
    __shared__ u16 Ahi[BM * ASTR];
    __shared__ u16 Alo[AMODE ? (BM * ASTR) : 8];
    __shared__ u16 Bhi[BN * ASTR];
    __shared__ u16 Blo[BN * ASTR];

    int tid = threadIdx.x;
    int wid = tid >> 6, lane = tid & 63;
    int wr = wid >> 1, wc = wid & 1;
    int r = lane & 15, h = lane >> 4;
    int bm0 = blockIdx.y * BM, bn0 = blockIdx.x * BN;
    // staging mapping: 16 rows x 4 granules per wave (matches MFMA read pattern -> 2-way max)
    int srow = (tid & 15) + 16 * (tid >> 6);   // +64*it
    int sg = (tid >> 4) & 3;                   // k-octet

    f32x4 acc[4][4];
#pragma unroll
    for (int i = 0; i < 4; ++i)
#pragma unroll
        for (int j = 0; j < 4; ++j) acc[i][j] = (f32x4){0.f, 0.f, 0.f, 0.f};

    for (int k0 = 0; k0 < Kd; k0 += BK) {
        __syncthreads();
        int kc = k0 + sg * 8;
        bool kok = (kc + 8 <= Kd);
        // ---- stage A [BM x BK]: 16B vector writes ----
#pragma unroll
        for (int it = 0; it < 2; ++it) {
            int row = srow + 64 * it;
            int gr = bm0 + row;
            u16* dst = Ahi + row * ASTR + sg * 8;
            if (AMODE == 0) {
                const u16* Ab = (const u16*)Av;
                uint4 v = make_uint4(0, 0, 0, 0);
                if (gr < Mr && kok) v = *(const uint4*)(Ab + (size_t)gr * Kd + kc);
                if (RELU_IN) {
                    v.x = relu2bf(v.x); v.y = relu2bf(v.y);
                    v.z = relu2bf(v.z); v.w = relu2bf(v.w);
                }
                *(uint4*)dst = v;
            } else {
                const float* Af = (const float*)Av;
                u32 hw[4] = {0, 0, 0, 0}, lw[4] = {0, 0, 0, 0};
                if (gr < Mr && kok) {
                    const float4* sp = (const float4*)(Af + (size_t)gr * Kd + kc);
                    float4 v0 = sp[0], v1 = sp[1];
                    float vs[8] = {v0.x, v0.y, v0.z, v0.w, v1.x, v1.y, v1.z, v1.w};
#pragma unroll
                    for (int qq = 0; qq < 4; ++qq) {
                        u16 h0 = f2bf(vs[2 * qq]), h1 = f2bf(vs[2 * qq + 1]);
                        hw[qq] = (u32)h0 | ((u32)h1 << 16);
                        u16 l0 = f2bf(vs[2 * qq] - bf2f(h0));
                        u16 l1 = f2bf(vs[2 * qq + 1] - bf2f(h1));
                        lw[qq] = (u32)l0 | ((u32)l1 << 16);
                    }
                }
                *(uint4*)dst = make_uint4(hw[0], hw[1], hw[2], hw[3]);
                *(uint4*)(Alo + row * ASTR + sg * 8) = make_uint4(lw[0], lw[1], lw[2], lw[3]);
            }
        }
        // ---- stage B [BK x BN] transposed to [n][k]: 16B vector writes ----
#pragma unroll
        for (int it = 0; it < 2; ++it) {
            int n = srow + 64 * it;
            int gn = bn0 + n;
            u32 hw[4] = {0, 0, 0, 0}, lw[4] = {0, 0, 0, 0};
            if (gn < Nc) {
#pragma unroll
                for (int qq = 0; qq < 4; ++qq) {
                    int gk0 = kc + 2 * qq, gk1 = kc + 2 * qq + 1;
                    float b0 = (gk0 < Kd) ? Bw[(size_t)gk0 * Nc + gn] : 0.f;
                    float b1 = (gk1 < Kd) ? Bw[(size_t)gk1 * Nc + gn] : 0.f;
                    u16 h0 = f2bf(b0), h1 = f2bf(b1);
                    hw[qq] = (u32)h0 | ((u32)h1 << 16);
                    u16 l0 = f2bf(b0 - bf2f(h0)), l1 = f2bf(b1 - bf2f(h1));
                    lw[qq] = (u32)l0 | ((u32)l1 << 16);
                }
            }
            *(uint4*)(Bhi + n * ASTR + sg * 8) = make_uint4(hw[0], hw[1], hw[2], hw[3]);
            *(uint4*)(Blo + n * ASTR + sg * 8) = make_uint4(lw[0], lw[1], lw[2], lw[3]);
        }
        __syncthreads();
        // ---- MFMA ----
        bf16x8 af[4], al[4], bh[4], bl[4];
#pragma unroll
        for (int j = 0; j < 4; ++j) {
            int nrow = wc * 64 + j * 16 + r;
            bh[j] = *(const bf16x8*)(Bhi + nrow * ASTR + h * 8);
            bl[j] = *(const bf16x8*)(Blo + nrow * ASTR + h * 8);
        }
#pragma unroll
        for (int i = 0; i < 4; ++i) {
            int mrow = wr * 64 + i * 16 + r;
            af[i] = *(const bf16x8*)(Ahi + mrow * ASTR + h * 8);
            if (AMODE) al[i] = *(const bf16x8*)(Alo + mrow * ASTR + h * 8);
        }
#pragma unroll
        for (int i = 0; i < 4; ++i)
#pragma unroll
            for (int j = 0; j < 4; ++j) {
                acc[i][j] = __builtin_amdgcn_mfma_f32_16x16x32_bf16(af[i], bh[j], acc[i][j], 0, 0, 0);
                acc[i][j] = __builtin_amdgcn_mfma_f32_16x16x32_bf16(af[i], bl[j], acc[i][j], 0, 0, 0);
                if (AMODE)
                    acc[i][j] = __builtin_amdgcn_mfma_f32_16x16x32_bf16(al[i], bh[j], acc[i][j], 0, 0, 0);
            }
    }
    // ---- epilogue: D col = bn0+wc*64+j*16+r, row = bm0+wr*64+i*16+h*4+rg ----
    float colacc[4] = {0.f, 0.f, 0.f, 0.f};
#pragma unroll
    for (int i = 0; i < 4; ++i) {
        float rowacc[4] = {0.f, 0.f, 0.f, 0.f};
#pragma unroll
        for (int j = 0; j < 4; ++j) {
            int col = bn0 + wc * 64 + j * 16 + r;
            bool colok = col < Nc;
            float tv = (FUSE == 2 && colok) ? tvec[col] : 0.f;
#pragma unroll
            for (int rg = 0; rg < 4; ++rg) {
                int row = bm0 + wr * 64 + i * 16 + h * 4 + rg;
                float v = acc[i][j][rg];
                if (HAS_BIAS && colok) v += bias[col];
                if (RELU_OUT) v = fmaxf(v, 0.f);
                bool ok = colok && row < Mr;
                if (HAS_ADD && ok) {
                    int r2 = addidx ? addidx[row] : row;
                    v += bf2f(addsrc[(size_t)r2 * Nc + col]);
                }
                if (FUSE != 2 && ok) stv(C, (size_t)row * Nc + col, v);
                if (FUSE == 1 && ok) colacc[j] += v;
                if (FUSE == 2) rowacc[rg] += v * tv;  // v==0 for col>=Nc / row>=Mr (zero-staged)
            }
        }
        if (FUSE == 2) {
#pragma unroll
            for (int rg = 0; rg < 4; ++rg) {
                float val = rowacc[rg];
                val += __shfl_xor(val, 1); val += __shfl_xor(val, 2);
                val += __shfl_xor(val, 4); val += __shfl_xor(val, 8);
                int row = bm0 + wr * 64 + i * 16 + h * 4 + rg;
                if (r == 0 && row < Mr) atomicAdd(&redout[row], val);
            }
        }
    }
    if (FUSE == 1) {
#pragma unroll
        for (int j = 0; j < 4; ++j) {
            float val = colacc[j];
            val += __shfl_xor(val, 16); val += __shfl_xor(val, 32);
            int col = bn0 + wc * 64 + j * 16 + r;
            if (h == 0 && col < Nc) atomicAdd(&redout[col], val);
        }
    }
}

// ---------------- DGI helpers ----------------
__global__ void k_sigc(const float* __restrict__ csum, float* __restrict__ cvec) {
    int i = threadIdx.x;
    cvec[i] = 1.0f / (1.0f + expf(-csum[i] * (1.0f / (float)NN)));
}

__global__ void k_tmv(const float* __restrict__ Wd, const float* __restrict__ cvec,
                      float* __restrict__ tvec) {
    __shared__ float c[HIDD];
    int lane = threadIdx.x;
    for (int j = lane; j < HIDD; j += 64) c[j] = cvec[j];
    __syncthreads();
    int r0 = blockIdx.x * 16;
    for (int i = r0; i < r0 + 16; ++i) {
        const float* wr = Wd + (size_t)i * HIDD;
        float s = 0.f;
        for (int j = lane; j < HIDD; j += 64) s += wr[j] * c[j];
        s = wredsum(s);
        if (lane == 0) tvec[i] = s;
    }
}

__global__ void k_rowdot512(const float* __restrict__ p, const float* __restrict__ t,
                            float* __restrict__ out, int rows) {
    int g = blockIdx.x * blockDim.x + threadIdx.x;
    int wv = g >> 6;
    if (wv >= rows) return;
    int lane = g & 63;
    const float* r = p + (size_t)wv * HIDD;
    float s = 0.f;
#pragma unroll
    for (int t4 = 0; t4 < 8; ++t4) {
        int d = lane + t4 * 64;
        s += r[d] * t[d];
    }
    s = wredsum(s);
    if (lane == 0) out[wv] = s;
}

// ---------------- ConvKB ----------------
__global__ void k_convkb(const u16* __restrict__ ec, const float* __restrict__ rel,
                         const int* __restrict__ bi, const float* __restrict__ cw,
                         const float* __restrict__ cb, const float* __restrict__ fcw,
                         const float* __restrict__ fcb, float* __restrict__ out) {
    __shared__ float t0[DD], t1[DD], t2[DD];
    __shared__ float red[4];
    int b = blockIdx.x, tid = threadIdx.x;
    int i0 = bi[b * 3 + 0], i1 = bi[b * 3 + 1], i2 = bi[b * 3 + 2];
    if (tid < DD) {
        t0[tid] = bf2f(ec[(size_t)i0 * DD + tid]);
        t1[tid] = rel[(size_t)i1 * DD + tid];
        t2[tid] = bf2f(ec[(size_t)i2 * DD + tid]);
    }
    __syncthreads();
    float partial = 0.f;
    if (tid < DD) {
        float a = t0[tid], bb = t1[tid], c = t2[tid];
        for (int o = 0; o < OCC; ++o) {
            float h = fmaxf(cw[o * 3 + 0] * a + cw[o * 3 + 1] * bb + cw[o * 3 + 2] * c + cb[o], 0.f);
            partial += h * fcw[o * DD + tid];
        }
    }
    partial = wredsum(partial);
    if ((tid & 63) == 0) red[tid >> 6] = partial;
    __syncthreads();
    if (tid == 0) out[b] = red[0] + red[1] + red[2] + red[3] + fcb[0];
}

__global__ void k_sentinel(float* out, float val) { out[threadIdx.x] = val; }

extern "C" void kernel_launch(void* const* d_in, const int* in_sizes, int n_in,
                              void* d_out, int out_size, void* d_ws, size_t ws_size,
                              hipStream_t stream) {
    const float* entity_emb = (const float*)d_in[0];
    const float* rel_emb    = (const float*)d_in[1];
    const int*   b_x        = (const int*)d_in[2];
    const int*   b_gi       = (const int*)d_in[3];
    const int*   e_src      = (const int*)d_in[4];
    const int*   e_dst      = (const int*)d_in[5];
    const float* e_w        = (const float*)d_in[6];
    const int*   big_src    = (const int*)d_in[7];
    const int*   big_dst    = (const int*)d_in[8];
    const float* big_w      = (const float*)d_in[9];
    const int*   perm       = (const int*)d_in[10];
    const int*   batch_in   = (const int*)d_in[11];
    const float* W1a        = (const float*)d_in[12];
    const float* W1b        = (const float*)d_in[13];
    const float* W2a        = (const float*)d_in[14];
    const float* W2b        = (const float*)d_in[15];
    // Wle/ble unused: segment softmax weights sum to exactly 1 and every row in a
    // segment shares the same emb vector -> pooled[n] == occ(n)*concat(e[n],mean[n])
    const float* Wlo        = (const float*)d_in[18];
    const float* blo        = (const float*)d_in[19];
    const float* Wg         = (const float*)d_in[20];
    const float* Wd         = (const float*)d_in[21];
    const float* conv_w     = (const float*)d_in[22];
    const float* conv_b     = (const float*)d_in[23];
    const float* fc_w       = (const float*)d_in[24];
    const float* fc_b       = (const float*)d_in[25];
    float* out = (float*)d_out;

    size_t off = 0;
    auto balloc = [&](size_t nbytes) {
        size_t p = off;
        off += (nbytes + 511) & ~(size_t)511;
        return p;
    };
    char* base = (char*)d_ws;
    u16*   entb = (u16*)(base + balloc((size_t)NN * DD * 2));
    float* relf = (float*)(base + balloc((size_t)RR * DD * 4));
    u16*   relb = (u16*)(base + balloc((size_t)RR * DD * 2));
    u16*   Pent = (u16*)(base + balloc((size_t)NN * HH1 * 2));
    u16*   Prel = (u16*)(base + balloc((size_t)RR * HH1 * 2));
    int*   idx1 = (int*)(base + balloc((size_t)MM * 4));
    u16*   ecb  = (u16*)(base + balloc((size_t)NN * DD * 2));
    int*   rpB  = (int*)(base + balloc((size_t)(NN + 1) * 4));
    int*   srcB = (int*)(base + balloc((size_t)NEE * 4));
    float* wB   = (float*)(base + balloc((size_t)NEE * 4));
    int*   rpE  = (int*)(base + balloc((size_t)(MM + 1) * 4));
    int*   srcE = (int*)(base + balloc((size_t)EE * 4));
    float* wE   = (float*)(base + balloc((size_t)EE * 4));
    int*   ivE  = (int*)(base + balloc((size_t)EE * 4));
    int*   giE  = (int*)(base + balloc((size_t)EE * 4));
    int*   rpX  = (int*)(base + balloc((size_t)(NN + 1) * 4));
    int*   mids = (int*)(base + balloc((size_t)MM * 4));
    int*   curB = (int*)(base + balloc((size_t)NN * 4));
    int*   curE = (int*)(base + balloc((size_t)MM * 4));
    int*   curX = (int*)(base + balloc((size_t)NN * 4));
    char*  Aarena = base + balloc((size_t)MM * HH1 * 2);   // 61.44 MB
    char*  Barena = base + balloc((size_t)MM * DD * 2);    // 48 MB
    char*  Carena = base + balloc((size_t)MM * DD * 2);    // 48 MB
    float* csum = (float*)(base + balloc(4 * 2048));
    float* cvec = csum + 512;
    float* t_l  = csum + 1024;
    float* t_g  = csum + 1536;

    if (ws_size < off) {
        k_sentinel<<<dim3(1), dim3(8), 0, stream>>>(out, (float)(ws_size >> 20));
        return;
    }

    u16*   aggx   = (u16*)Aarena;                 // [MM,256] bf16
    u16*   hb     = (u16*)Barena;                 // [MM,200] bf16
    u16*   e_buf  = (u16*)Carena;                 // [MM,200] bf16
    u16*   pooled = (u16*)Aarena;                 // [NN,400] bf16 (aggx dead)
    float* a1f    = (float*)Aarena;               // [NN,200] f32
    float* h2f    = (float*)Barena;               // [NN,256] f32 (spans B..C)
    float* h2bf   = (float*)Aarena;               // [NN,200] f32
    float* egf    = (float*)Carena;               // [NN,200] f32
    float* pbuf   = (float*)Aarena;               // [NN,512] f32 (spans A..B)

    dim3 blk(256);
    auto wgrid = [](int items) { return dim3((unsigned)((items + 3) / 4)); };
    auto tgrid = [](int items) { return dim3((unsigned)((items + 255) / 256)); };
    auto mmgrid = [](int Mr, int Nc) { return dim3((unsigned)((Nc + 127) / 128), (unsigned)((Mr + 127) / 128)); };

    // ---- normalize + perm gather ----
    k_l2norm<<<wgrid(NN), blk, 0, stream>>>(entity_emb, nullptr, entb, NN);
    k_l2norm<<<wgrid(RR), blk, 0, stream>>>(rel_emb, relf, relb, RR);
    k_gather_perm<<<tgrid(MM), blk, 0, stream>>>(b_x, perm, idx1, MM);

    // ---- CSR builds ----
    hipMemsetAsync(curB, 0, (size_t)NN * 4, stream);
    hipMemsetAsync(curE, 0, (size_t)MM * 4, stream);
    hipMemsetAsync(curX, 0, (size_t)NN * 4, stream);
    k_hist<<<tgrid(NEE), blk, 0, stream>>>(big_dst, curB, NEE);
    k_hist<<<tgrid(EE), blk, 0, stream>>>(e_dst, curE, EE);
    k_hist<<<tgrid(MM), blk, 0, stream>>>(b_x, curX, MM);
    k_scan<<<dim3(1), dim3(1024), 0, stream>>>(curB, rpB, NN);
    k_scan<<<dim3(1), dim3(1024), 0, stream>>>(curE, rpE, MM);
    k_scan<<<dim3(1), dim3(1024), 0, stream>>>(curX, rpX, NN);
    hipMemcpyAsync(curB, rpB, (size_t)NN * 4, hipMemcpyDeviceToDevice, stream);
    hipMemcpyAsync(curE, rpE, (size_t)MM * 4, hipMemcpyDeviceToDevice, stream);
    hipMemcpyAsync(curX, rpX, (size_t)NN * 4, hipMemcpyDeviceToDevice, stream);
    k_fill2<<<tgrid(NEE), blk, 0, stream>>>(big_dst, big_src, big_w, curB, srcB, wB, NEE);
    k_fill2<<<tgrid(EE), blk, 0, stream>>>(e_dst, e_src, e_w, curE, srcE, wE, EE);
    k_fill1<<<tgrid(MM), blk, 0, stream>>>(b_x, curX, mids, MM);
    k_edge_idx<<<tgrid(EE), blk, 0, stream>>>(srcE, b_gi, giE, EE);

    // ---- P_ent = ent @ W1a[:200], P_rel = rel @ W1a[200:] ----
    k_mfmamm<0, 0, 0, 0, 0, 0, u16><<<mmgrid(NN, HH1), blk, 0, stream>>>(
        entb, W1a, Pent, NN, HH1, DD, nullptr, nullptr, nullptr, nullptr, nullptr);
    k_mfmamm<0, 0, 0, 0, 0, 0, u16><<<mmgrid(RR, HH1), blk, 0, stream>>>(
        relb, W1a + (size_t)DD * HH1, Prel, RR, HH1, DD, nullptr, nullptr, nullptr, nullptr, nullptr);

    for (int v = 0; v < 2; ++v) {
        const int* ivmap  = v ? idx1 : b_x;
        const int* addidx = v ? perm : nullptr;

        // --- MCE via fused pull aggregation ---
        k_edge_idx<<<tgrid(EE), blk, 0, stream>>>(srcE, ivmap, ivE, EE);
        k_pull_mce<<<wgrid(MM), blk, 0, stream>>>(rpE, ivE, giE, wE, Pent, Prel, aggx, MM);
        k_mfmamm<0, 1, 0, 0, 0, 0, u16><<<mmgrid(MM, DD), blk, 0, stream>>>(
            aggx, W1b, hb, MM, DD, HH1, nullptr, nullptr, nullptr, nullptr, nullptr);
        k_pull<DD, u16, u16><<<wgrid(MM), blk, 0, stream>>>(rpE, srcE, wE, hb, e_buf, MM);
        k_segpool<<<wgrid(NN), blk, 0, stream>>>(rpX, mids, e_buf, pooled, NN);
        k_mfmamm<0, 0, 0, 1, 1, 0, u16><<<mmgrid(NN, DD), blk, 0, stream>>>(
            pooled, Wlo, ecb, NN, DD, 2 * DD, blo, entb, addidx, nullptr, nullptr);

        // --- DGI local ---
        if (v == 0) {
            hipMemsetAsync(csum, 0, 512 * sizeof(float), stream);
            k_mfmamm<0, 0, 1, 0, 0, 1, float><<<mmgrid(NN, HIDD), blk, 0, stream>>>(
                ecb, Wg, pbuf, NN, HIDD, DD, nullptr, nullptr, nullptr, nullptr, csum);
            k_sigc<<<dim3(1), dim3(512), 0, stream>>>(csum, cvec);
            k_tmv<<<dim3(32), dim3(64), 0, stream>>>(Wd, cvec, t_l);
            k_rowdot512<<<wgrid(NN), blk, 0, stream>>>(pbuf, t_l, out + BB, NN);
            k_convkb<<<dim3(BB), blk, 0, stream>>>(ecb, relf, batch_in,
                                                   conv_w, conv_b, fc_w, fc_b, out);
        } else {
            hipMemsetAsync(out + BB + NN, 0, (size_t)NN * 4, stream);
            k_mfmamm<0, 0, 1, 0, 0, 2, float><<<mmgrid(NN, HIDD), blk, 0, stream>>>(
                ecb, Wg, nullptr, NN, HIDD, DD, nullptr, nullptr, nullptr, t_l, out + BB + NN);
        }

        // --- big GCN (f32 chain, split-MFMA) ---
        k_pull<DD, u16, float><<<wgrid(NN), blk, 0, stream>>>(rpB, srcB, wB, ecb, a1f, NN);
        k_mfmamm<1, 0, 1, 0, 0, 0, float><<<mmgrid(NN, HH1), blk, 0, stream>>>(
            a1f, W2a, h2f, NN, HH1, DD, nullptr, nullptr, nullptr, nullptr, nullptr);
        k_mfmamm<1, 0, 0, 0, 0, 0, float><<<mmgrid(NN, DD), blk, 0, stream>>>(
            h2f, W2b, h2bf, NN, DD, HH1, nullptr, nullptr, nullptr, nullptr, nullptr);
        k_pull<DD, float, float><<<wgrid(NN), blk, 0, stream>>>(rpB, srcB, wB, h2bf, egf, NN);

        // --- DGI global ---
        if (v == 0) {
            hipMemsetAsync(csum, 0, 512 * sizeof(float), stream);
            k_mfmamm<1, 0, 1, 0, 0, 1, float><<<mmgrid(NN, HIDD), blk, 0, stream>>>(
                egf, Wg, pbuf, NN, HIDD, DD, nullptr, nullptr, nullptr, nullptr, csum);
            k_sigc<<<dim3(1), dim3(512), 0, stream>>>(csum, cvec);
            k_tmv<<<dim3(32), dim3(64), 0, stream>>>(Wd, cvec, t_g);
            k_rowdot512<<<wgrid(NN), blk, 0, stream>>>(pbuf, t_g, out + BB + 2 * (size_t)NN, NN);
        } else {
            hipMemsetAsync(out + BB + 3 * (size_t)NN, 0, (size_t)NN * 4, stream);
            k_mfmamm<1, 0, 1, 0, 0, 2, float><<<mmgrid(NN, HIDD), blk, 0, stream>>>(
                egf, Wg, nullptr, NN, HIDD, DD, nullptr, nullptr, nullptr, t_g,
                out + BB + 3 * (size_t)NN);
        }
    }

    (void)in_sizes; (void)n_in; (void)out_size;
}